// Round 3
// baseline (2012.995 us; speedup 1.0000x reference)
//
#include <hip/hip_runtime.h>
#include <hip/hip_bf16.h>

#define NN 50000
#define EE 800000
#define HH 128

typedef __attribute__((ext_vector_type(8))) short bf16x8;
typedef __attribute__((ext_vector_type(4))) float f32x4;

__device__ inline unsigned short f2bf(float f) {
    union { float f; unsigned u; } v; v.f = f;
    unsigned r = v.u + 0x7FFF + ((v.u >> 16) & 1);
    return (unsigned short)(r >> 16);
}

// ---------------- CSR build (edges grouped by dst) ----------------
__global__ __launch_bounds__(256) void hist_k(const int* __restrict__ dst, int* __restrict__ cnt) {
    int i = blockIdx.x * 256 + threadIdx.x;
    if (i < EE) atomicAdd(&cnt[dst[i]], 1);
}

__global__ __launch_bounds__(256) void blocksum_k(const int* __restrict__ cnt, int* __restrict__ bsum) {
    __shared__ int sm[256];
    int i = blockIdx.x * 256 + threadIdx.x;
    sm[threadIdx.x] = (i < NN) ? cnt[i] : 0;
    __syncthreads();
    for (int s = 128; s > 0; s >>= 1) {
        if (threadIdx.x < s) sm[threadIdx.x] += sm[threadIdx.x + s];
        __syncthreads();
    }
    if (threadIdx.x == 0) bsum[blockIdx.x] = sm[0];
}

__global__ __launch_bounds__(256) void scanb_k(int* __restrict__ bsum, int nb) {
    __shared__ int sm[256];
    int t = threadIdx.x;
    sm[t] = (t < nb) ? bsum[t] : 0;
    __syncthreads();
    for (int d = 1; d < 256; d <<= 1) {
        int v = (t >= d) ? sm[t - d] : 0;
        __syncthreads();
        sm[t] += v;
        __syncthreads();
    }
    if (t < nb) bsum[t] = sm[t];
}

__global__ __launch_bounds__(256) void offsets_k(const int* __restrict__ cnt, const int* __restrict__ bsum,
                                                 int* __restrict__ offsets, int* __restrict__ cursor) {
    __shared__ int sm[256];
    int b = blockIdx.x, t = threadIdx.x;
    int i = b * 256 + t;
    int c = (i < NN) ? cnt[i] : 0;
    sm[t] = c;
    __syncthreads();
    for (int d = 1; d < 256; d <<= 1) {
        int v = (t >= d) ? sm[t - d] : 0;
        __syncthreads();
        sm[t] += v;
        __syncthreads();
    }
    int incl = sm[t];
    int base = (b == 0) ? 0 : bsum[b - 1];
    int off = base + incl - c;
    if (i < NN) { offsets[i] = off; cursor[i] = off; }
    if (i == NN - 1) offsets[NN] = off + c;
}

__global__ __launch_bounds__(256) void fill_k(const int* __restrict__ dst, int* __restrict__ cursor,
                                              int* __restrict__ eids) {
    int i = blockIdx.x * 256 + threadIdx.x;
    if (i < EE) { int p = atomicAdd(&cursor[dst[i]], 1); eids[p] = i; }
}

// ---------------- weight prep: W[fi][fo] f32 -> W_t[n][k] bf16 (plain transpose) ----------------
__global__ __launch_bounds__(256) void wprep_k(const float* __restrict__ W, unsigned short* __restrict__ out,
                                               int fi, int fo, int n_off, int out_ld) {
    int i = blockIdx.x * 256 + threadIdx.x;
    if (i >= fi * fo) return;
    int n = i / fi, k = i - n * fi;
    out[(size_t)(n_off + n) * out_ld + k] = f2bf(W[(size_t)k * fo + n]);
}

// ---------------- MFMA gather-GEMM, barrier-free ----------------
// C[M, NCW*128 per block] = act( concat_g Ag[idx_g(row)] @ W + bias )
// 4 waves / 256 threads, NO LDS, NO barriers: W is small (<=96KB..128KB) and
// L2-resident, so each wave loads its B fragments directly from L2 into regs.
//   (three rounds of LDS-staged variants all pinned at ~600us: the per-k-step
//    global_load_lds + __syncthreads vmcnt(0) drain exposes full load latency
//    per step and more waves don't help. Barrier-free waves free-run.)
// Per-wave tile 32x128: M_rep=2 x N_rep=8 of 16x16x32 bf16 MFMA, BK=32.
// NCW=1: block = 4 row-waves = 128 rows x 128 cols.
// NCW=2: block = 2 row x 2 col waves = 64 rows x 256 cols (col-waves share the
//        A rows; the duplicate A loads hit L2, so e is read once from HBM).
// A: direct global loads (f32->bf16 inline, or bf16 passthrough per bfmask bit).
// mode: 0 f32, 1 f32+relu, 2 bf16, 4 bf16+relu, 3 relu+resid+LayerNorm(128) f32.
template <int NCW>
__global__ __launch_bounds__(256, 3) void mm_k(
    const void* __restrict__ A0, const int* __restrict__ idx0,
    const void* __restrict__ A1, const int* __restrict__ idx1,
    const void* __restrict__ A2, const int* __restrict__ idx2,
    int bfmask,
    const unsigned short* __restrict__ Wt, const float* __restrict__ bias,
    int M, int Ktot, int mode,
    float* __restrict__ Cf, unsigned short* __restrict__ Cb, int out_ld,
    const float* __restrict__ resid, const float* __restrict__ gamma, const float* __restrict__ beta)
{
    const int t = threadIdx.x;
    const int wid = t >> 6, lane = t & 63;
    const int colw = (NCW == 1) ? 0 : (wid & (NCW - 1));
    const int roww = (NCW == 1) ? wid : (wid >> 1);
    const int ROWS = (4 / NCW) * 32;         // rows per block
    const int lr = lane & 15, lk = lane >> 4;
    const int col0 = colw << 7;              // first output col of this wave
    const int wrow = blockIdx.x * ROWS + roww * 32;

    int r0 = wrow + lr;      if (r0 >= M) r0 = M - 1;
    int r1 = wrow + 16 + lr; if (r1 >= M) r1 = M - 1;

    const int ng = Ktot >> 7;   // 128-k groups

    f32x4 acc[2][8];
    #pragma unroll
    for (int i = 0; i < 2; ++i)
        #pragma unroll
        for (int j = 0; j < 8; ++j) acc[i][j] = (f32x4){0.f, 0.f, 0.f, 0.f};

    for (int g = 0; g < ng; ++g) {
        const void* Ag = (g == 0) ? A0 : ((g == 1) ? A1 : A2);
        const int* ig  = (g == 0) ? idx0 : ((g == 1) ? idx1 : idx2);
        const int isbf = (bfmask >> g) & 1;
        const int rid0 = ig ? ig[r0] : r0;
        const int rid1 = ig ? ig[r1] : r1;
        const char* Ab = (const char*)Ag;

        #pragma unroll
        for (int ks = 0; ks < 4; ++ks) {
            const int st = (g << 2) + ks;
            const size_t kel = (size_t)(ks << 5) + (lk << 3);

            // A fragments (2 rows x 8 bf16)
            bf16x8 a0, a1;
            if (isbf) {
                a0 = *(const bf16x8*)(Ab + (((size_t)rid0 * HH + kel) << 1));
                a1 = *(const bf16x8*)(Ab + (((size_t)rid1 * HH + kel) << 1));
            } else {
                const float* p0 = (const float*)Ab + (size_t)rid0 * HH + kel;
                const float* p1 = (const float*)Ab + (size_t)rid1 * HH + kel;
                float4 u0 = *(const float4*)p0, u1 = *(const float4*)(p0 + 4);
                float4 v0 = *(const float4*)p1, v1 = *(const float4*)(p1 + 4);
                a0 = (bf16x8){(short)f2bf(u0.x), (short)f2bf(u0.y), (short)f2bf(u0.z), (short)f2bf(u0.w),
                              (short)f2bf(u1.x), (short)f2bf(u1.y), (short)f2bf(u1.z), (short)f2bf(u1.w)};
                a1 = (bf16x8){(short)f2bf(v0.x), (short)f2bf(v0.y), (short)f2bf(v0.z), (short)f2bf(v0.w),
                              (short)f2bf(v1.x), (short)f2bf(v1.y), (short)f2bf(v1.z), (short)f2bf(v1.w)};
            }

            // B fragments straight from L2: Wt[(col0 + nf*16 + lr)][st*32 + lk*8]
            const unsigned short* wb = Wt + (size_t)(col0 + lr) * Ktot + (st << 5) + (lk << 3);
            bf16x8 b[8];
            #pragma unroll
            for (int nf = 0; nf < 8; ++nf)
                b[nf] = *(const bf16x8*)(wb + (size_t)(nf << 4) * Ktot);

            #pragma unroll
            for (int nf = 0; nf < 8; ++nf) {
                acc[0][nf] = __builtin_amdgcn_mfma_f32_16x16x32_bf16(a0, b[nf], acc[0][nf], 0, 0, 0);
                acc[1][nf] = __builtin_amdgcn_mfma_f32_16x16x32_bf16(a1, b[nf], acc[1][nf], 0, 0, 0);
            }
        }
    }

    // ---------------- epilogue ----------------
    float bias8[8];
    #pragma unroll
    for (int nf = 0; nf < 8; ++nf) bias8[nf] = bias[col0 + (nf << 4) + lr];

    if (mode == 3) {
        float g8[8], be8[8];
        #pragma unroll
        for (int nf = 0; nf < 8; ++nf) { g8[nf] = gamma[(nf << 4) + lr]; be8[nf] = beta[(nf << 4) + lr]; }
        #pragma unroll
        for (int mf = 0; mf < 2; ++mf) {
            #pragma unroll
            for (int rr = 0; rr < 4; ++rr) {
                int row = wrow + mf * 16 + lk * 4 + rr;
                bool ok = row < M;
                int rowc = ok ? row : M - 1;
                float x[8], sum = 0.f;
                #pragma unroll
                for (int nf = 0; nf < 8; ++nf) {
                    float v = fmaxf(acc[mf][nf][rr] + bias8[nf], 0.f);
                    v += resid[(size_t)rowc * HH + (nf << 4) + lr];
                    x[nf] = v; sum += v;
                }
                sum += __shfl_xor(sum, 1); sum += __shfl_xor(sum, 2);
                sum += __shfl_xor(sum, 4); sum += __shfl_xor(sum, 8);
                const float mean = sum * (1.f / 128.f);
                float vs = 0.f;
                #pragma unroll
                for (int nf = 0; nf < 8; ++nf) { float d = x[nf] - mean; vs += d * d; }
                vs += __shfl_xor(vs, 1); vs += __shfl_xor(vs, 2);
                vs += __shfl_xor(vs, 4); vs += __shfl_xor(vs, 8);
                const float rs = rsqrtf(vs * (1.f / 128.f) + 1e-5f);
                if (ok) {
                    #pragma unroll
                    for (int nf = 0; nf < 8; ++nf)
                        Cf[(size_t)row * out_ld + (nf << 4) + lr] = (x[nf] - mean) * rs * g8[nf] + be8[nf];
                }
            }
        }
    } else {
        #pragma unroll
        for (int mf = 0; mf < 2; ++mf) {
            #pragma unroll
            for (int rr = 0; rr < 4; ++rr) {
                int row = wrow + mf * 16 + lk * 4 + rr;
                if (row >= M) continue;
                #pragma unroll
                for (int nf = 0; nf < 8; ++nf) {
                    float v = acc[mf][nf][rr] + bias8[nf];
                    if (mode == 1 || mode == 4) v = fmaxf(v, 0.f);
                    size_t o = (size_t)row * out_ld + col0 + (nf << 4) + lr;
                    if (mode == 0 || mode == 1) Cf[o] = v;
                    else Cb[o] = f2bf(v);
                }
            }
        }
    }
}

// ---------------- attention scores: s[e,h] = <Q[dst[e],h,:], K[e,h,:]> / sqrt(32) ----------------
__global__ __launch_bounds__(256) void score_k(const float* __restrict__ Q,
                                               const __hip_bfloat16* __restrict__ KV,
                                               const int* __restrict__ dst,
                                               float* __restrict__ s)
{
    const int t = threadIdx.x;
    const int e = blockIdx.x * 2 + (t >> 7);
    const int c = t & 127;
    const int d = dst[e];
    const float q = Q[(size_t)d * HH + c];
    const float k = __bfloat162float(KV[(size_t)e * 256 + c]);
    float p = q * k;
    p += __shfl_xor(p, 16); p += __shfl_xor(p, 8);
    p += __shfl_xor(p, 4);  p += __shfl_xor(p, 2); p += __shfl_xor(p, 1);
    if ((t & 31) == 0) s[(size_t)e * 4 + (c >> 5)] = p * 0.17677669529663687f;
}

// ---------------- per-node online-softmax aggregation (one wave per node) ----------------
__global__ __launch_bounds__(256) void agg_k(const __hip_bfloat16* __restrict__ KV,
                                             const float* __restrict__ s,
                                             const int* __restrict__ offsets,
                                             const int* __restrict__ eids,
                                             float* __restrict__ hagg)
{
    const int t = threadIdx.x;
    const int n = blockIdx.x * 4 + (t >> 6);
    if (n >= NN) return;
    const int lane = t & 63;
    const int c0 = lane, c1 = lane + 64;
    const int h0 = lane >> 5, h1 = h0 + 2;
    const int o0 = offsets[n], o1 = offsets[n + 1];
    float m0 = -1e30f, m1 = -1e30f, d0 = 0.f, d1 = 0.f, a0 = 0.f, a1 = 0.f;
    for (int j = o0; j < o1; ++j) {
        const int e = eids[j];
        const float s0 = s[(size_t)e * 4 + h0];
        const float s1 = s[(size_t)e * 4 + h1];
        const float v0 = __bfloat162float(KV[(size_t)e * 256 + 128 + c0]);
        const float v1 = __bfloat162float(KV[(size_t)e * 256 + 128 + c1]);
        float nm = fmaxf(m0, s0);
        float sc = __expf(m0 - nm);
        float w  = __expf(s0 - nm);
        d0 = d0 * sc + w; a0 = a0 * sc + w * v0; m0 = nm;
        nm = fmaxf(m1, s1);
        sc = __expf(m1 - nm);
        w  = __expf(s1 - nm);
        d1 = d1 * sc + w; a1 = a1 * sc + w * v1; m1 = nm;
    }
    const bool any = (o1 > o0);
    hagg[(size_t)n * HH + c0] = any ? (a0 / d0) : 0.f;
    hagg[(size_t)n * HH + c1] = any ? (a1 / d1) : 0.f;
}

extern "C" void kernel_launch(void* const* d_in, const int* in_sizes, int n_in,
                              void* d_out, int out_size, void* d_ws, size_t ws_size,
                              hipStream_t stream)
{
    const float* h   = (const float*)d_in[0];
    const float* e   = (const float*)d_in[1];
    const int*   src = (const int*)d_in[2];
    const int*   dst = (const int*)d_in[3];
    const float* Wq  = (const float*)d_in[4];
    const float* bq  = (const float*)d_in[5];
    const float* Wk  = (const float*)d_in[6];
    const float* bk  = (const float*)d_in[7];
    const float* Wv  = (const float*)d_in[8];
    const float* bv  = (const float*)d_in[9];
    const float* Wn1 = (const float*)d_in[10];
    const float* bn1 = (const float*)d_in[11];
    const float* Wn2 = (const float*)d_in[12];
    const float* bn2 = (const float*)d_in[13];
    const float* We1 = (const float*)d_in[14];
    const float* be1 = (const float*)d_in[15];
    const float* We2 = (const float*)d_in[16];
    const float* be2 = (const float*)d_in[17];
    const float* gh  = (const float*)d_in[18];
    const float* bh  = (const float*)d_in[19];
    const float* ge  = (const float*)d_in[20];
    const float* be_ = (const float*)d_in[21];
    (void)in_sizes; (void)n_in; (void)out_size; (void)ws_size;

    float* h_out = (float*)d_out;
    float* e_out = (float*)d_out + (size_t)NN * HH;

    char* ws = (char*)d_ws;
    size_t off = 0;
    auto carve = [&](size_t bytes) { void* p = ws + off; off += (bytes + 255) & ~(size_t)255; return p; };
    __hip_bfloat16* KV = (__hip_bfloat16*)carve((size_t)EE * 256 * 2); // reused as t_edge (bf16 [E][128]) after agg
    unsigned short* t_edge = (unsigned short*)KV;
    float* Q      = (float*)carve((size_t)NN * HH * 4);
    float* sbuf   = (float*)carve((size_t)EE * 4 * 4);
    float* hagg   = (float*)carve((size_t)NN * HH * 4);
    float* tnode  = (float*)carve((size_t)NN * HH * 4);
    int* cursor   = (int*)carve((size_t)NN * 4);
    int* offsets  = (int*)carve((size_t)(NN + 1) * 4);
    int* bsum     = (int*)carve(256 * 4);
    int* eids     = (int*)carve((size_t)EE * 4);
    unsigned short* Wq_s  = (unsigned short*)carve(128 * 128 * 2);
    unsigned short* Wkv_s = (unsigned short*)carve(256 * 256 * 2);
    unsigned short* Wn1_s = (unsigned short*)carve(128 * 128 * 2);
    unsigned short* Wn2_s = (unsigned short*)carve(128 * 128 * 2);
    unsigned short* We1_s = (unsigned short*)carve(128 * 384 * 2);
    unsigned short* We2_s = (unsigned short*)carve(128 * 128 * 2);
    float* b_kv   = (float*)carve(256 * 4);

    const int nb = (NN + 255) / 256;

    // weight prep (bf16 transpose) + combined KV bias
    wprep_k<<<(128 * 128 + 255) / 256, 256, 0, stream>>>(Wq,  Wq_s,  128, 128, 0, 128);
    wprep_k<<<(256 * 128 + 255) / 256, 256, 0, stream>>>(Wk,  Wkv_s, 256, 128, 0, 256);
    wprep_k<<<(256 * 128 + 255) / 256, 256, 0, stream>>>(Wv,  Wkv_s, 256, 128, 128, 256);
    wprep_k<<<(128 * 128 + 255) / 256, 256, 0, stream>>>(Wn1, Wn1_s, 128, 128, 0, 128);
    wprep_k<<<(128 * 128 + 255) / 256, 256, 0, stream>>>(Wn2, Wn2_s, 128, 128, 0, 128);
    wprep_k<<<(384 * 128 + 255) / 256, 256, 0, stream>>>(We1, We1_s, 384, 128, 0, 384);
    wprep_k<<<(128 * 128 + 255) / 256, 256, 0, stream>>>(We2, We2_s, 128, 128, 0, 128);
    hipMemcpyAsync(b_kv,       bk, 128 * 4, hipMemcpyDeviceToDevice, stream);
    hipMemcpyAsync(b_kv + 128, bv, 128 * 4, hipMemcpyDeviceToDevice, stream);

    // CSR build
    hipMemsetAsync(cursor, 0, (size_t)NN * 4, stream);
    hist_k<<<(EE + 255) / 256, 256, 0, stream>>>(dst, cursor);
    blocksum_k<<<nb, 256, 0, stream>>>(cursor, bsum);
    scanb_k<<<1, 256, 0, stream>>>(bsum, nb);
    offsets_k<<<nb, 256, 0, stream>>>(cursor, bsum, offsets, cursor);
    fill_k<<<(EE + 255) / 256, 256, 0, stream>>>(dst, cursor, eids);

    // Q = h @ Wq + bq  (f32 out)  [128 rows/block]
    mm_k<1><<<dim3((NN + 127) / 128, 1), 256, 0, stream>>>(
        h, nullptr, nullptr, nullptr, nullptr, nullptr, 0,
        Wq_s, bq, NN, 128, 0, Q, nullptr, 128, nullptr, nullptr, nullptr);

    // K|V = [h[src], e] @ [Wk|Wv] + [bk|bv]  (bf16 interleaved [E][256])
    // NCW=2: 64x256 block, col-waves share the A stream -> e read once from HBM
    mm_k<2><<<dim3(EE / 64, 1), 256, 0, stream>>>(
        h, src, e, nullptr, nullptr, nullptr, 0,
        Wkv_s, b_kv, EE, 256, 2, nullptr, (unsigned short*)KV, 256, nullptr, nullptr, nullptr);

    score_k<<<EE / 2, 256, 0, stream>>>(Q, KV, dst, sbuf);
    agg_k<<<(NN + 3) / 4, 256, 0, stream>>>(KV, sbuf, offsets, eids, hagg);

    // node MLP + residual + LN -> h_out
    mm_k<1><<<dim3((NN + 127) / 128, 1), 256, 0, stream>>>(
        hagg, nullptr, nullptr, nullptr, nullptr, nullptr, 0,
        Wn1_s, bn1, NN, 128, 1, tnode, nullptr, 128, nullptr, nullptr, nullptr);
    mm_k<1><<<dim3((NN + 127) / 128, 1), 256, 0, stream>>>(
        tnode, nullptr, nullptr, nullptr, nullptr, nullptr, 0,
        Wn2_s, bn2, NN, 128, 3, h_out, nullptr, 128, h, gh, bh);

    // edge MLP on [h_out[src], h_out[dst], e] + residual + LN -> e_out
    mm_k<1><<<dim3(EE / 128, 1), 256, 0, stream>>>(
        h_out, src, h_out, dst, e, nullptr, 0,
        We1_s, be1, EE, 384, 4, nullptr, t_edge, 128, nullptr, nullptr, nullptr);
    mm_k<1><<<dim3(EE / 128, 1), 256, 0, stream>>>(
        t_edge, nullptr, nullptr, nullptr, nullptr, nullptr, 1,
        We2_s, be2, EE, 128, 3, e_out, nullptr, 128, e, ge, be_);
}

// Round 4
// 2002.987 us; speedup vs baseline: 1.0050x; 1.0050x over previous
//
#include <hip/hip_runtime.h>
#include <hip/hip_bf16.h>

#define NN 50000
#define EE 800000
#define HH 128

typedef __attribute__((ext_vector_type(8))) short bf16x8;
typedef __attribute__((ext_vector_type(4))) float f32x4;

__device__ inline unsigned short f2bf(float f) {
    union { float f; unsigned u; } v; v.f = f;
    unsigned r = v.u + 0x7FFF + ((v.u >> 16) & 1);
    return (unsigned short)(r >> 16);
}

// ---------------- CSR build (edges grouped by dst) ----------------
__global__ __launch_bounds__(256) void hist_k(const int* __restrict__ dst, int* __restrict__ cnt) {
    int i = blockIdx.x * 256 + threadIdx.x;
    if (i < EE) atomicAdd(&cnt[dst[i]], 1);
}

__global__ __launch_bounds__(256) void blocksum_k(const int* __restrict__ cnt, int* __restrict__ bsum) {
    __shared__ int sm[256];
    int i = blockIdx.x * 256 + threadIdx.x;
    sm[threadIdx.x] = (i < NN) ? cnt[i] : 0;
    __syncthreads();
    for (int s = 128; s > 0; s >>= 1) {
        if (threadIdx.x < s) sm[threadIdx.x] += sm[threadIdx.x + s];
        __syncthreads();
    }
    if (threadIdx.x == 0) bsum[blockIdx.x] = sm[0];
}

__global__ __launch_bounds__(256) void scanb_k(int* __restrict__ bsum, int nb) {
    __shared__ int sm[256];
    int t = threadIdx.x;
    sm[t] = (t < nb) ? bsum[t] : 0;
    __syncthreads();
    for (int d = 1; d < 256; d <<= 1) {
        int v = (t >= d) ? sm[t - d] : 0;
        __syncthreads();
        sm[t] += v;
        __syncthreads();
    }
    if (t < nb) bsum[t] = sm[t];
}

__global__ __launch_bounds__(256) void offsets_k(const int* __restrict__ cnt, const int* __restrict__ bsum,
                                                 int* __restrict__ offsets, int* __restrict__ cursor) {
    __shared__ int sm[256];
    int b = blockIdx.x, t = threadIdx.x;
    int i = b * 256 + t;
    int c = (i < NN) ? cnt[i] : 0;
    sm[t] = c;
    __syncthreads();
    for (int d = 1; d < 256; d <<= 1) {
        int v = (t >= d) ? sm[t - d] : 0;
        __syncthreads();
        sm[t] += v;
        __syncthreads();
    }
    int incl = sm[t];
    int base = (b == 0) ? 0 : bsum[b - 1];
    int off = base + incl - c;
    if (i < NN) { offsets[i] = off; cursor[i] = off; }
    if (i == NN - 1) offsets[NN] = off + c;
}

__global__ __launch_bounds__(256) void fill_k(const int* __restrict__ dst, int* __restrict__ cursor,
                                              int* __restrict__ eids) {
    int i = blockIdx.x * 256 + threadIdx.x;
    if (i < EE) { int p = atomicAdd(&cursor[dst[i]], 1); eids[p] = i; }
}

// ---------------- weight prep: W[fi][fo] f32 -> W_t[n][k] bf16 (plain transpose) ----------------
__global__ __launch_bounds__(256) void wprep_k(const float* __restrict__ W, unsigned short* __restrict__ out,
                                               int fi, int fo, int n_off, int out_ld) {
    int i = blockIdx.x * 256 + threadIdx.x;
    if (i >= fi * fo) return;
    int n = i / fi, k = i - n * fi;
    out[(size_t)(n_off + n) * out_ld + k] = f2bf(W[(size_t)k * fo + n]);
}

// ---------------- f32 -> bf16 bulk convert (8 elems/thread) ----------------
__global__ __launch_bounds__(256) void cvt_k(const float* __restrict__ in, unsigned short* __restrict__ out,
                                             long n8) {
    long i = (long)blockIdx.x * 256 + threadIdx.x;
    if (i >= n8) return;
    const float4* p = (const float4*)in + i * 2;
    float4 a = p[0], b = p[1];
    bf16x8 o = {(short)f2bf(a.x), (short)f2bf(a.y), (short)f2bf(a.z), (short)f2bf(a.w),
                (short)f2bf(b.x), (short)f2bf(b.y), (short)f2bf(b.z), (short)f2bf(b.w)};
    *((bf16x8*)out + i) = o;
}

// ---------------- B-stationary MFMA gather-GEMM (no LDS, no barriers) ----------------
// C[M, NCW*NF*16] = act( concat_g Ag[idx_g(row)] @ W + bias ), all A operands bf16.
// Rationale: K<=384 and 32..128 cols/wave mean a wave's whole B panel fits in
// 32..128 VGPRs, loaded ONCE per kernel. Waves then stream independent 16-row
// A tiles: per tile only KS a-loads + KS*NF MFMAs. No per-k-step B motion, no
// barrier convoy (4 prior LDS/L2-staged structures all pinned at 560-720us with
// MfmaUtil ~7% regardless of occupancy).
// 512 threads = 8 waves: colw = wid%NCW (NF*16 cols each), roww = wid/NCW.
// All NCW col-waves of a row share the A stream -> duplicate A reads hit L1/L2,
// HBM once (KV: e read once). Row indices for all RT tiles prefetched up front.
// mode: 0 f32, 1 f32+relu, 2 bf16, 4 bf16+relu, 3 relu+resid+LayerNorm(128) f32.
template <int NF, int KS, int RT, int NCW>
__global__ __launch_bounds__(512, 2) void mm2_k(
    const unsigned short* __restrict__ A0, const int* __restrict__ idx0,
    const unsigned short* __restrict__ A1, const int* __restrict__ idx1,
    const unsigned short* __restrict__ A2, const int* __restrict__ idx2,
    const unsigned short* __restrict__ Wt, const float* __restrict__ bias,
    int M, int mode,
    float* __restrict__ Cf, unsigned short* __restrict__ Cb, int out_ld,
    const float* __restrict__ resid, const float* __restrict__ gamma, const float* __restrict__ beta)
{
    constexpr int G = KS / 4;        // 128-k input groups
    constexpr int Ktot = KS * 32;
    constexpr int RW = 8 / NCW;      // row-wave groups
    const int t = threadIdx.x;
    const int wid = t >> 6, lane = t & 63;
    const int lr = lane & 15, lk = lane >> 4;
    const int colw = wid % NCW, roww = wid / NCW;
    const int col0 = colw * (NF * 16);

    const unsigned short* As[3] = {A0, A1, A2};
    const int* igs[3] = {idx0, idx1, idx2};

    // B panel: held in registers for the whole kernel (loaded once, from L2)
    bf16x8 b[KS][NF];
    #pragma unroll
    for (int s = 0; s < KS; ++s)
        #pragma unroll
        for (int c = 0; c < NF; ++c)
            b[s][c] = *(const bf16x8*)(Wt + (size_t)(col0 + c * 16 + lr) * Ktot + s * 32 + lk * 8);

    float bias8[NF];
    #pragma unroll
    for (int c = 0; c < NF; ++c) bias8[c] = bias[col0 + c * 16 + lr];

    float g8[NF], be8[NF];
    if (NF == 8 && mode == 3) {
        #pragma unroll
        for (int c = 0; c < NF; ++c) { g8[c] = gamma[c * 16 + lr]; be8[c] = beta[c * 16 + lr]; }
    }

    const int tbase = blockIdx.x * (RW * RT);

    // prefetch row gather indices for all tiles/groups (breaks idx->A serial chain)
    int rids[G][RT];
    #pragma unroll
    for (int tt = 0; tt < RT; ++tt) {
        const int tile = tbase + tt * RW + roww;
        int r = tile * 16 + lr;
        if (r >= M) r = M - 1;
        #pragma unroll
        for (int g = 0; g < G; ++g)
            rids[g][tt] = igs[g] ? igs[g][r] : r;
    }

    #pragma unroll
    for (int tt = 0; tt < RT; ++tt) {
        const int trow = (tbase + tt * RW + roww) * 16;

        // A fragments for this 16-row tile
        bf16x8 a[KS];
        #pragma unroll
        for (int s = 0; s < KS; ++s) {
            const int g = s >> 2;
            a[s] = *(const bf16x8*)(As[g] + (size_t)rids[g][tt] * HH + (s & 3) * 32 + lk * 8);
        }

        f32x4 acc[NF];
        #pragma unroll
        for (int c = 0; c < NF; ++c) acc[c] = (f32x4){0.f, 0.f, 0.f, 0.f};
        #pragma unroll
        for (int s = 0; s < KS; ++s)
            #pragma unroll
            for (int c = 0; c < NF; ++c)
                acc[c] = __builtin_amdgcn_mfma_f32_16x16x32_bf16(a[s], b[s][c], acc[c], 0, 0, 0);

        // ---------------- epilogue ----------------
        if (NF == 8 && mode == 3) {
            #pragma unroll
            for (int rr = 0; rr < 4; ++rr) {
                int row = trow + lk * 4 + rr;
                bool ok = row < M;
                int rowc = ok ? row : M - 1;
                float x[8], sum = 0.f;
                #pragma unroll
                for (int c = 0; c < 8; ++c) {
                    float v = fmaxf(acc[c][rr] + bias8[c], 0.f);
                    v += resid[(size_t)rowc * HH + (c << 4) + lr];
                    x[c] = v; sum += v;
                }
                sum += __shfl_xor(sum, 1); sum += __shfl_xor(sum, 2);
                sum += __shfl_xor(sum, 4); sum += __shfl_xor(sum, 8);
                const float mean = sum * (1.f / 128.f);
                float vs = 0.f;
                #pragma unroll
                for (int c = 0; c < 8; ++c) { float d = x[c] - mean; vs += d * d; }
                vs += __shfl_xor(vs, 1); vs += __shfl_xor(vs, 2);
                vs += __shfl_xor(vs, 4); vs += __shfl_xor(vs, 8);
                const float rs = rsqrtf(vs * (1.f / 128.f) + 1e-5f);
                if (ok) {
                    #pragma unroll
                    for (int c = 0; c < 8; ++c)
                        Cf[(size_t)row * out_ld + (c << 4) + lr] = (x[c] - mean) * rs * g8[c] + be8[c];
                }
            }
        } else {
            #pragma unroll
            for (int rr = 0; rr < 4; ++rr) {
                int row = trow + lk * 4 + rr;
                if (row >= M) continue;
                #pragma unroll
                for (int c = 0; c < NF; ++c) {
                    float v = acc[c][rr] + bias8[c];
                    if (mode == 1 || mode == 4) v = fmaxf(v, 0.f);
                    size_t o = (size_t)row * out_ld + col0 + (c << 4) + lr;
                    if (mode == 0 || mode == 1) Cf[o] = v;
                    else Cb[o] = f2bf(v);
                }
            }
        }
    }
}

// ---------------- attention scores: s[e,h] = <Q[dst[e],h,:], K[e,h,:]> / sqrt(32) ----------------
__global__ __launch_bounds__(256) void score_k(const float* __restrict__ Q,
                                               const __hip_bfloat16* __restrict__ KV,
                                               const int* __restrict__ dst,
                                               float* __restrict__ s)
{
    const int t = threadIdx.x;
    const int e = blockIdx.x * 2 + (t >> 7);
    const int c = t & 127;
    const int d = dst[e];
    const float q = Q[(size_t)d * HH + c];
    const float k = __bfloat162float(KV[(size_t)e * 256 + c]);
    float p = q * k;
    p += __shfl_xor(p, 16); p += __shfl_xor(p, 8);
    p += __shfl_xor(p, 4);  p += __shfl_xor(p, 2); p += __shfl_xor(p, 1);
    if ((t & 31) == 0) s[(size_t)e * 4 + (c >> 5)] = p * 0.17677669529663687f;
}

// ---------------- per-node online-softmax aggregation (one wave per node) ----------------
__global__ __launch_bounds__(256) void agg_k(const __hip_bfloat16* __restrict__ KV,
                                             const float* __restrict__ s,
                                             const int* __restrict__ offsets,
                                             const int* __restrict__ eids,
                                             unsigned short* __restrict__ hagg)
{
    const int t = threadIdx.x;
    const int n = blockIdx.x * 4 + (t >> 6);
    if (n >= NN) return;
    const int lane = t & 63;
    const int c0 = lane, c1 = lane + 64;
    const int h0 = lane >> 5, h1 = h0 + 2;
    const int o0 = offsets[n], o1 = offsets[n + 1];
    float m0 = -1e30f, m1 = -1e30f, d0 = 0.f, d1 = 0.f, a0 = 0.f, a1 = 0.f;
    for (int j = o0; j < o1; ++j) {
        const int e = eids[j];
        const float s0 = s[(size_t)e * 4 + h0];
        const float s1 = s[(size_t)e * 4 + h1];
        const float v0 = __bfloat162float(KV[(size_t)e * 256 + 128 + c0]);
        const float v1 = __bfloat162float(KV[(size_t)e * 256 + 128 + c1]);
        float nm = fmaxf(m0, s0);
        float sc = __expf(m0 - nm);
        float w  = __expf(s0 - nm);
        d0 = d0 * sc + w; a0 = a0 * sc + w * v0; m0 = nm;
        nm = fmaxf(m1, s1);
        sc = __expf(m1 - nm);
        w  = __expf(s1 - nm);
        d1 = d1 * sc + w; a1 = a1 * sc + w * v1; m1 = nm;
    }
    const bool any = (o1 > o0);
    hagg[(size_t)n * HH + c0] = any ? f2bf(a0 / d0) : 0;
    hagg[(size_t)n * HH + c1] = any ? f2bf(a1 / d1) : 0;
}

extern "C" void kernel_launch(void* const* d_in, const int* in_sizes, int n_in,
                              void* d_out, int out_size, void* d_ws, size_t ws_size,
                              hipStream_t stream)
{
    const float* h   = (const float*)d_in[0];
    const float* e   = (const float*)d_in[1];
    const int*   src = (const int*)d_in[2];
    const int*   dst = (const int*)d_in[3];
    const float* Wq  = (const float*)d_in[4];
    const float* bq  = (const float*)d_in[5];
    const float* Wk  = (const float*)d_in[6];
    const float* bk  = (const float*)d_in[7];
    const float* Wv  = (const float*)d_in[8];
    const float* bv  = (const float*)d_in[9];
    const float* Wn1 = (const float*)d_in[10];
    const float* bn1 = (const float*)d_in[11];
    const float* Wn2 = (const float*)d_in[12];
    const float* bn2 = (const float*)d_in[13];
    const float* We1 = (const float*)d_in[14];
    const float* be1 = (const float*)d_in[15];
    const float* We2 = (const float*)d_in[16];
    const float* be2 = (const float*)d_in[17];
    const float* gh  = (const float*)d_in[18];
    const float* bh  = (const float*)d_in[19];
    const float* ge  = (const float*)d_in[20];
    const float* be_ = (const float*)d_in[21];
    (void)in_sizes; (void)n_in; (void)out_size; (void)ws_size;

    float* h_out = (float*)d_out;
    float* e_out = (float*)d_out + (size_t)NN * HH;

    char* ws = (char*)d_ws;
    size_t off = 0;
    auto carve = [&](size_t bytes) { void* p = ws + off; off += (bytes + 255) & ~(size_t)255; return p; };
    __hip_bfloat16* KV = (__hip_bfloat16*)carve((size_t)EE * 256 * 2); // reused as t_edge (bf16 [E][128]) after agg
    unsigned short* t_edge = (unsigned short*)KV;
    unsigned short* ebf = (unsigned short*)carve((size_t)EE * HH * 2); // e in bf16
    float* Q      = (float*)carve((size_t)NN * HH * 4);                // reused as tnode (bf16) after score
    unsigned short* tnode = (unsigned short*)Q;
    float* sbuf   = (float*)carve((size_t)EE * 4 * 4);
    unsigned short* hagg = (unsigned short*)carve((size_t)NN * HH * 2); // reused as hobf after Wn1
    unsigned short* hobf = hagg;
    unsigned short* hbf  = (unsigned short*)carve((size_t)NN * HH * 2);
    int* cursor   = (int*)carve((size_t)NN * 4);
    int* offsets  = (int*)carve((size_t)(NN + 1) * 4);
    int* bsum     = (int*)carve(256 * 4);
    int* eids     = (int*)carve((size_t)EE * 4);
    unsigned short* Wq_s  = (unsigned short*)carve(128 * 128 * 2);
    unsigned short* Wkv_s = (unsigned short*)carve(256 * 256 * 2);
    unsigned short* Wn1_s = (unsigned short*)carve(128 * 128 * 2);
    unsigned short* Wn2_s = (unsigned short*)carve(128 * 128 * 2);
    unsigned short* We1_s = (unsigned short*)carve(128 * 384 * 2);
    unsigned short* We2_s = (unsigned short*)carve(128 * 128 * 2);
    float* b_kv   = (float*)carve(256 * 4);

    const int nb = (NN + 255) / 256;

    // weight prep (bf16 transpose) + combined KV bias
    wprep_k<<<(128 * 128 + 255) / 256, 256, 0, stream>>>(Wq,  Wq_s,  128, 128, 0, 128);
    wprep_k<<<(256 * 128 + 255) / 256, 256, 0, stream>>>(Wk,  Wkv_s, 256, 128, 0, 256);
    wprep_k<<<(256 * 128 + 255) / 256, 256, 0, stream>>>(Wv,  Wkv_s, 256, 128, 128, 256);
    wprep_k<<<(128 * 128 + 255) / 256, 256, 0, stream>>>(Wn1, Wn1_s, 128, 128, 0, 128);
    wprep_k<<<(128 * 128 + 255) / 256, 256, 0, stream>>>(Wn2, Wn2_s, 128, 128, 0, 128);
    wprep_k<<<(384 * 128 + 255) / 256, 256, 0, stream>>>(We1, We1_s, 384, 128, 0, 384);
    wprep_k<<<(128 * 128 + 255) / 256, 256, 0, stream>>>(We2, We2_s, 128, 128, 0, 128);
    hipMemcpyAsync(b_kv,       bk, 128 * 4, hipMemcpyDeviceToDevice, stream);
    hipMemcpyAsync(b_kv + 128, bv, 128 * 4, hipMemcpyDeviceToDevice, stream);

    // activations -> bf16 (one-time; same rounding as the old inline f2bf path)
    cvt_k<<<(NN * HH / 8 + 255) / 256, 256, 0, stream>>>(h, hbf, (long)NN * HH / 8);
    cvt_k<<<(EE * HH / 8 + 255) / 256, 256, 0, stream>>>(e, ebf, (long)EE * HH / 8);

    // CSR build
    hipMemsetAsync(cursor, 0, (size_t)NN * 4, stream);
    hist_k<<<(EE + 255) / 256, 256, 0, stream>>>(dst, cursor);
    blocksum_k<<<nb, 256, 0, stream>>>(cursor, bsum);
    scanb_k<<<1, 256, 0, stream>>>(bsum, nb);
    offsets_k<<<nb, 256, 0, stream>>>(cursor, bsum, offsets, cursor);
    fill_k<<<(EE + 255) / 256, 256, 0, stream>>>(dst, cursor, eids);

    // Q = h @ Wq + bq  (f32 out)   [128 cols: NCW=4, RW=2, 128 rows/block]
    mm2_k<2, 4, 4, 4><<<(NN + 127) / 128, 512, 0, stream>>>(
        hbf, nullptr, nullptr, nullptr, nullptr, nullptr,
        Wq_s, bq, NN, 0, Q, nullptr, 128, nullptr, nullptr, nullptr);

    // K|V = [h[src], e] @ [Wk|Wv] + [bk|bv]  (bf16 interleaved [E][256])
    // 256 cols: NCW=8, RW=1, RT=8 -> 128 rows/block; e read once (8 col-waves share A via L1)
    mm2_k<2, 8, 8, 8><<<EE / 128, 512, 0, stream>>>(
        hbf, src, ebf, nullptr, nullptr, nullptr,
        Wkv_s, b_kv, EE, 2, nullptr, (unsigned short*)KV, 256, nullptr, nullptr, nullptr);

    score_k<<<EE / 2, 256, 0, stream>>>(Q, KV, dst, sbuf);
    agg_k<<<(NN + 3) / 4, 256, 0, stream>>>(KV, sbuf, offsets, eids, hagg);

    // node MLP + residual + LN -> h_out
    mm2_k<2, 4, 4, 4><<<(NN + 127) / 128, 512, 0, stream>>>(
        hagg, nullptr, nullptr, nullptr, nullptr, nullptr,
        Wn1_s, bn1, NN, 4, nullptr, tnode, 128, nullptr, nullptr, nullptr);
    mm2_k<8, 4, 2, 1><<<(NN + 255) / 256, 512, 0, stream>>>(
        tnode, nullptr, nullptr, nullptr, nullptr, nullptr,
        Wn2_s, bn2, NN, 3, h_out, nullptr, 128, h, gh, bh);

    // h_out -> bf16 for the edge-MLP gathers
    cvt_k<<<(NN * HH / 8 + 255) / 256, 256, 0, stream>>>(h_out, hobf, (long)NN * HH / 8);

    // edge MLP on [h_out[src], h_out[dst], e] + residual + LN -> e_out
    mm2_k<2, 12, 4, 4><<<EE / 128, 512, 0, stream>>>(
        hobf, src, hobf, dst, ebf, nullptr,
        We1_s, be1, EE, 4, nullptr, t_edge, 128, nullptr, nullptr, nullptr);
    mm2_k<8, 4, 2, 1><<<EE / 256, 512, 0, stream>>>(
        t_edge, nullptr, nullptr, nullptr, nullptr, nullptr,
        We2_s, be2, EE, 3, e_out, nullptr, 128, e, ge, be_);
}

// Round 5
// 1748.285 us; speedup vs baseline: 1.1514x; 1.1457x over previous
//
#include <hip/hip_runtime.h>
#include <hip/hip_bf16.h>

#define NN 50000
#define EE 800000
#define HH 128

typedef __attribute__((ext_vector_type(8))) short bf16x8;
typedef __attribute__((ext_vector_type(4))) float f32x4;

__device__ inline unsigned short f2bf(float f) {
    union { float f; unsigned u; } v; v.f = f;
    unsigned r = v.u + 0x7FFF + ((v.u >> 16) & 1);
    return (unsigned short)(r >> 16);
}

// ---------------- CSR build (edges grouped by dst) ----------------
__global__ __launch_bounds__(256) void hist_k(const int* __restrict__ dst, int* __restrict__ cnt) {
    int i = blockIdx.x * 256 + threadIdx.x;
    if (i < EE) atomicAdd(&cnt[dst[i]], 1);
}

__global__ __launch_bounds__(256) void blocksum_k(const int* __restrict__ cnt, int* __restrict__ bsum) {
    __shared__ int sm[256];
    int i = blockIdx.x * 256 + threadIdx.x;
    sm[threadIdx.x] = (i < NN) ? cnt[i] : 0;
    __syncthreads();
    for (int s = 128; s > 0; s >>= 1) {
        if (threadIdx.x < s) sm[threadIdx.x] += sm[threadIdx.x + s];
        __syncthreads();
    }
    if (threadIdx.x == 0) bsum[blockIdx.x] = sm[0];
}

__global__ __launch_bounds__(256) void scanb_k(int* __restrict__ bsum, int nb) {
    __shared__ int sm[256];
    int t = threadIdx.x;
    sm[t] = (t < nb) ? bsum[t] : 0;
    __syncthreads();
    for (int d = 1; d < 256; d <<= 1) {
        int v = (t >= d) ? sm[t - d] : 0;
        __syncthreads();
        sm[t] += v;
        __syncthreads();
    }
    if (t < nb) bsum[t] = sm[t];
}

__global__ __launch_bounds__(256) void offsets_k(const int* __restrict__ cnt, const int* __restrict__ bsum,
                                                 int* __restrict__ offsets, int* __restrict__ cursor) {
    __shared__ int sm[256];
    int b = blockIdx.x, t = threadIdx.x;
    int i = b * 256 + t;
    int c = (i < NN) ? cnt[i] : 0;
    sm[t] = c;
    __syncthreads();
    for (int d = 1; d < 256; d <<= 1) {
        int v = (t >= d) ? sm[t - d] : 0;
        __syncthreads();
        sm[t] += v;
        __syncthreads();
    }
    int incl = sm[t];
    int base = (b == 0) ? 0 : bsum[b - 1];
    int off = base + incl - c;
    if (i < NN) { offsets[i] = off; cursor[i] = off; }
    if (i == NN - 1) offsets[NN] = off + c;
}

__global__ __launch_bounds__(256) void fill_k(const int* __restrict__ dst, int* __restrict__ cursor,
                                              int* __restrict__ eids) {
    int i = blockIdx.x * 256 + threadIdx.x;
    if (i < EE) { int p = atomicAdd(&cursor[dst[i]], 1); eids[p] = i; }
}

// ---------------- weight prep: W[fi][fo] f32 -> W_t[n][k] bf16 (plain transpose) ----------------
__global__ __launch_bounds__(256) void wprep_k(const float* __restrict__ W, unsigned short* __restrict__ out,
                                               int fi, int fo, int n_off, int out_ld) {
    int i = blockIdx.x * 256 + threadIdx.x;
    if (i >= fi * fo) return;
    int n = i / fi, k = i - n * fi;
    out[(size_t)(n_off + n) * out_ld + k] = f2bf(W[(size_t)k * fo + n]);
}

// ---------------- f32 -> bf16 bulk convert (8 elems/thread) ----------------
__global__ __launch_bounds__(256) void cvt_k(const float* __restrict__ in, unsigned short* __restrict__ out,
                                             long n8) {
    long i = (long)blockIdx.x * 256 + threadIdx.x;
    if (i >= n8) return;
    const float4* p = (const float4*)in + i * 2;
    float4 a = p[0], b = p[1];
    bf16x8 o = {(short)f2bf(a.x), (short)f2bf(a.y), (short)f2bf(a.z), (short)f2bf(a.w),
                (short)f2bf(b.x), (short)f2bf(b.y), (short)f2bf(b.z), (short)f2bf(b.w)};
    *((bf16x8*)out + i) = o;
}

// ---------------- chunked MFMA gather-GEMM: A in LDS (per 128-k chunk), B in regs ----------------
// C[M, NCW*32] = act( concat_g Ag[idx_g(row)] @ W + bias ), A operands bf16 [*][128].
// 8 waves = RW(=8/NCW) row-waves x NCW col-waves; per-wave tile 16 rows x 32 cols
// (2 x 16x16x32 MFMA per k-step), RT tiles per row-wave; ROWS = RW*RT*16 per block.
// Per chunk g (128 k): stage A_g rows into LDS via global_load_lds (coalesced
// 256B/row, XOR-swizzled source so ds_read_b128 is 2-way-conflict-free), load
// B_g chunk into 32 VGPRs, ONE barrier, then RT x (4 ds_read + 8 MFMA).
//   - barriers at chunk granularity (1-3 per kernel), not per k-step (R0-R2's
//     per-step convoy pinned at ~600us) and no scattered per-fragment global
//     loads (R3/R4's 16-segment transaction amplification pinned at ~520us).
//   - B panel is 32 VGPR for every variant -> no spills (R4's NF=8 spilled).
// MODE: 0 f32, 1 f32+relu, 2 bf16, 4 bf16+relu, 3 relu+resid+LayerNorm(128) f32
// (MODE 3 reduces across the 4 col-waves via a small LDS buffer + 1 barrier).
template <int G, int NCW, int RT, int MODE>
__global__ __launch_bounds__(512, 2) void mm3_k(
    const unsigned short* __restrict__ A0, const int* __restrict__ idx0,
    const unsigned short* __restrict__ A1, const int* __restrict__ idx1,
    const unsigned short* __restrict__ A2, const int* __restrict__ idx2,
    const unsigned short* __restrict__ Wt, const float* __restrict__ bias,
    int M,
    float* __restrict__ Cf, unsigned short* __restrict__ Cb, int out_ld,
    const float* __restrict__ resid, const float* __restrict__ gamma, const float* __restrict__ beta)
{
    constexpr int RW = 8 / NCW;
    constexpr int ROWS = RW * RT * 16;
    constexpr int Ktot = G * 128;
    constexpr int SI = ROWS / 32;            // global_load_lds issues per thread per chunk
    __shared__ unsigned short Asl[ROWS * 128];
    __shared__ float lnbuf[(MODE == 3) ? RT * 32 * 8 : 8];

    const int t = threadIdx.x;
    const int wid = t >> 6, lane = t & 63;
    const int lr = lane & 15, lk = lane >> 4;
    const int colw = (NCW == 8) ? wid : (wid & 3);
    const int roww = (NCW == 8) ? 0 : (wid >> 2);
    const int col0 = colw << 5;
    const int tbase = blockIdx.x * ROWS;

    const unsigned short* As[3] = {A0, A1, A2};
    const int* igs[3] = {idx0, idx1, idx2};

    f32x4 acc[RT][2];
    #pragma unroll
    for (int tt = 0; tt < RT; ++tt) { acc[tt][0] = (f32x4){0,0,0,0}; acc[tt][1] = (f32x4){0,0,0,0}; }

    for (int g = 0; g < G; ++g) {
        if (g) __syncthreads();   // all ds_reads of chunk g-1 done before overwrite

        // stage A_g: LDS[row][c16] = Ag[rid(row)][ (c16 ^ (row&7)) * 8 .. +8 ]
        // (source pre-swizzled per-lane; LDS dest linear: wave-uniform base + lane*16)
        const unsigned short* Ag = As[g];
        const int* ig = igs[g];
        #pragma unroll
        for (int i = 0; i < SI; ++i) {
            int rl = ((i * 8 + wid) << 2) + (lane >> 4);     // block-local row
            int gr = tbase + rl; if (gr >= M) gr = M - 1;
            int rid = ig ? ig[gr] : gr;
            const unsigned short* src = Ag + (size_t)rid * HH + (((lane & 15) ^ (rl & 7)) << 3);
            unsigned short* dst = &Asl[(i * 8 + wid) << 9];
            __builtin_amdgcn_global_load_lds((const __attribute__((address_space(1))) void*)src,
                                             (__attribute__((address_space(3))) void*)dst, 16, 0, 0);
        }

        // B chunk: 4 k-steps x 2 col-fragments = 32 VGPR, loaded from L2
        bf16x8 b[4][2];
        #pragma unroll
        for (int s = 0; s < 4; ++s)
            #pragma unroll
            for (int c = 0; c < 2; ++c)
                b[s][c] = *(const bf16x8*)(Wt + (size_t)(col0 + (c << 4) + lr) * Ktot + (g << 7) + (s << 5) + (lk << 3));

        __syncthreads();

        #pragma unroll
        for (int tt = 0; tt < RT; ++tt) {
            const int tl = (tt * RW + roww) << 4;
            bf16x8 a[4];
            #pragma unroll
            for (int s = 0; s < 4; ++s) {
                const int c16 = ((s << 2) + lk) ^ (lr & 7);
                a[s] = *(const bf16x8*)&Asl[((tl + lr) << 7) + (c16 << 3)];
            }
            #pragma unroll
            for (int s = 0; s < 4; ++s) {
                acc[tt][0] = __builtin_amdgcn_mfma_f32_16x16x32_bf16(a[s], b[s][0], acc[tt][0], 0, 0, 0);
                acc[tt][1] = __builtin_amdgcn_mfma_f32_16x16x32_bf16(a[s], b[s][1], acc[tt][1], 0, 0, 0);
            }
        }
    }

    // ---------------- epilogue ----------------
    float bias2[2] = {bias[col0 + lr], bias[col0 + 16 + lr]};

    if (MODE == 3) {
        float g2[2] = {gamma[col0 + lr], gamma[col0 + 16 + lr]};
        float be2[2] = {beta[col0 + lr], beta[col0 + 16 + lr]};
        // phase A: relu+bias+resid into acc, per-row partial (sum, sumsq) over this
        // wave's 32 cols -> shfl-reduce over lr -> lnbuf[tile][rowlocal][colw]
        #pragma unroll
        for (int tt = 0; tt < RT; ++tt) {
            #pragma unroll
            for (int rr = 0; rr < 4; ++rr) {
                int row = tbase + ((tt * RW + roww) << 4) + (lk << 2) + rr;
                int rowc = (row < M) ? row : M - 1;
                float sum = 0.f, sq = 0.f;
                #pragma unroll
                for (int c = 0; c < 2; ++c) {
                    float v = fmaxf(acc[tt][c][rr] + bias2[c], 0.f);
                    v += resid[(size_t)rowc * HH + col0 + (c << 4) + lr];
                    acc[tt][c][rr] = v;
                    sum += v; sq += v * v;
                }
                sum += __shfl_xor(sum, 1); sq += __shfl_xor(sq, 1);
                sum += __shfl_xor(sum, 2); sq += __shfl_xor(sq, 2);
                sum += __shfl_xor(sum, 4); sq += __shfl_xor(sq, 4);
                sum += __shfl_xor(sum, 8); sq += __shfl_xor(sq, 8);
                if (lr == 0) {
                    int rls = (roww << 4) + (lk << 2) + rr;       // 0..31
                    lnbuf[((tt * 32 + rls) << 3) + (colw << 1) + 0] = sum;
                    lnbuf[((tt * 32 + rls) << 3) + (colw << 1) + 1] = sq;
                }
            }
        }
        __syncthreads();
        // phase B: combine 4 col-wave partials, normalize, store
        #pragma unroll
        for (int tt = 0; tt < RT; ++tt) {
            #pragma unroll
            for (int rr = 0; rr < 4; ++rr) {
                int rls = (roww << 4) + (lk << 2) + rr;
                float s4 = 0.f, q4 = 0.f;
                #pragma unroll
                for (int cw = 0; cw < 4; ++cw) {
                    s4 += lnbuf[((tt * 32 + rls) << 3) + (cw << 1) + 0];
                    q4 += lnbuf[((tt * 32 + rls) << 3) + (cw << 1) + 1];
                }
                const float mean = s4 * (1.f / 128.f);
                const float var = q4 * (1.f / 128.f) - mean * mean;
                const float rs = rsqrtf(var + 1e-5f);
                int row = tbase + ((tt * RW + roww) << 4) + (lk << 2) + rr;
                if (row < M) {
                    #pragma unroll
                    for (int c = 0; c < 2; ++c)
                        Cf[(size_t)row * out_ld + col0 + (c << 4) + lr] =
                            (acc[tt][c][rr] - mean) * rs * g2[c] + be2[c];
                }
            }
        }
    } else {
        #pragma unroll
        for (int tt = 0; tt < RT; ++tt) {
            #pragma unroll
            for (int rr = 0; rr < 4; ++rr) {
                int row = tbase + ((tt * RW + roww) << 4) + (lk << 2) + rr;
                if (row >= M) continue;
                #pragma unroll
                for (int c = 0; c < 2; ++c) {
                    float v = acc[tt][c][rr] + bias2[c];
                    if (MODE == 1 || MODE == 4) v = fmaxf(v, 0.f);
                    size_t o = (size_t)row * out_ld + col0 + (c << 4) + lr;
                    if (MODE == 0 || MODE == 1) Cf[o] = v;
                    else Cb[o] = f2bf(v);
                }
            }
        }
    }
}

// ---------------- attention scores: s[e,h] = <Q[dst[e],h,:], K[e,h,:]> / sqrt(32) ----------------
__global__ __launch_bounds__(256) void score_k(const float* __restrict__ Q,
                                               const __hip_bfloat16* __restrict__ KV,
                                               const int* __restrict__ dst,
                                               float* __restrict__ s)
{
    const int t = threadIdx.x;
    const int e = blockIdx.x * 2 + (t >> 7);
    const int c = t & 127;
    const int d = dst[e];
    const float q = Q[(size_t)d * HH + c];
    const float k = __bfloat162float(KV[(size_t)e * 256 + c]);
    float p = q * k;
    p += __shfl_xor(p, 16); p += __shfl_xor(p, 8);
    p += __shfl_xor(p, 4);  p += __shfl_xor(p, 2); p += __shfl_xor(p, 1);
    if ((t & 31) == 0) s[(size_t)e * 4 + (c >> 5)] = p * 0.17677669529663687f;
}

// ---------------- per-node online-softmax aggregation (one wave per node) ----------------
__global__ __launch_bounds__(256) void agg_k(const __hip_bfloat16* __restrict__ KV,
                                             const float* __restrict__ s,
                                             const int* __restrict__ offsets,
                                             const int* __restrict__ eids,
                                             unsigned short* __restrict__ hagg)
{
    const int t = threadIdx.x;
    const int n = blockIdx.x * 4 + (t >> 6);
    if (n >= NN) return;
    const int lane = t & 63;
    const int c0 = lane, c1 = lane + 64;
    const int h0 = lane >> 5, h1 = h0 + 2;
    const int o0 = offsets[n], o1 = offsets[n + 1];
    float m0 = -1e30f, m1 = -1e30f, d0 = 0.f, d1 = 0.f, a0 = 0.f, a1 = 0.f;
    for (int j = o0; j < o1; ++j) {
        const int e = eids[j];
        const float s0 = s[(size_t)e * 4 + h0];
        const float s1 = s[(size_t)e * 4 + h1];
        const float v0 = __bfloat162float(KV[(size_t)e * 256 + 128 + c0]);
        const float v1 = __bfloat162float(KV[(size_t)e * 256 + 128 + c1]);
        float nm = fmaxf(m0, s0);
        float sc = __expf(m0 - nm);
        float w  = __expf(s0 - nm);
        d0 = d0 * sc + w; a0 = a0 * sc + w * v0; m0 = nm;
        nm = fmaxf(m1, s1);
        sc = __expf(m1 - nm);
        w  = __expf(s1 - nm);
        d1 = d1 * sc + w; a1 = a1 * sc + w * v1; m1 = nm;
    }
    const bool any = (o1 > o0);
    hagg[(size_t)n * HH + c0] = any ? f2bf(a0 / d0) : 0;
    hagg[(size_t)n * HH + c1] = any ? f2bf(a1 / d1) : 0;
}

extern "C" void kernel_launch(void* const* d_in, const int* in_sizes, int n_in,
                              void* d_out, int out_size, void* d_ws, size_t ws_size,
                              hipStream_t stream)
{
    const float* h   = (const float*)d_in[0];
    const float* e   = (const float*)d_in[1];
    const int*   src = (const int*)d_in[2];
    const int*   dst = (const int*)d_in[3];
    const float* Wq  = (const float*)d_in[4];
    const float* bq  = (const float*)d_in[5];
    const float* Wk  = (const float*)d_in[6];
    const float* bk  = (const float*)d_in[7];
    const float* Wv  = (const float*)d_in[8];
    const float* bv  = (const float*)d_in[9];
    const float* Wn1 = (const float*)d_in[10];
    const float* bn1 = (const float*)d_in[11];
    const float* Wn2 = (const float*)d_in[12];
    const float* bn2 = (const float*)d_in[13];
    const float* We1 = (const float*)d_in[14];
    const float* be1 = (const float*)d_in[15];
    const float* We2 = (const float*)d_in[16];
    const float* be2 = (const float*)d_in[17];
    const float* gh  = (const float*)d_in[18];
    const float* bh  = (const float*)d_in[19];
    const float* ge  = (const float*)d_in[20];
    const float* be_ = (const float*)d_in[21];
    (void)in_sizes; (void)n_in; (void)out_size; (void)ws_size;

    float* h_out = (float*)d_out;
    float* e_out = (float*)d_out + (size_t)NN * HH;

    char* ws = (char*)d_ws;
    size_t off = 0;
    auto carve = [&](size_t bytes) { void* p = ws + off; off += (bytes + 255) & ~(size_t)255; return p; };
    __hip_bfloat16* KV = (__hip_bfloat16*)carve((size_t)EE * 256 * 2); // reused as t_edge (bf16 [E][128]) after agg
    unsigned short* t_edge = (unsigned short*)KV;
    unsigned short* ebf = (unsigned short*)carve((size_t)EE * HH * 2); // e in bf16
    float* Q      = (float*)carve((size_t)NN * HH * 4);                // reused as tnode (bf16) after score
    unsigned short* tnode = (unsigned short*)Q;
    float* sbuf   = (float*)carve((size_t)EE * 4 * 4);
    unsigned short* hagg = (unsigned short*)carve((size_t)NN * HH * 2); // reused as hobf after Wn1
    unsigned short* hobf = hagg;
    unsigned short* hbf  = (unsigned short*)carve((size_t)NN * HH * 2);
    int* cursor   = (int*)carve((size_t)NN * 4);
    int* offsets  = (int*)carve((size_t)(NN + 1) * 4);
    int* bsum     = (int*)carve(256 * 4);
    int* eids     = (int*)carve((size_t)EE * 4);
    unsigned short* Wq_s  = (unsigned short*)carve(128 * 128 * 2);
    unsigned short* Wkv_s = (unsigned short*)carve(256 * 256 * 2);
    unsigned short* Wn1_s = (unsigned short*)carve(128 * 128 * 2);
    unsigned short* Wn2_s = (unsigned short*)carve(128 * 128 * 2);
    unsigned short* We1_s = (unsigned short*)carve(128 * 384 * 2);
    unsigned short* We2_s = (unsigned short*)carve(128 * 128 * 2);
    float* b_kv   = (float*)carve(256 * 4);

    const int nb = (NN + 255) / 256;

    // weight prep (bf16 transpose) + combined KV bias
    wprep_k<<<(128 * 128 + 255) / 256, 256, 0, stream>>>(Wq,  Wq_s,  128, 128, 0, 128);
    wprep_k<<<(256 * 128 + 255) / 256, 256, 0, stream>>>(Wk,  Wkv_s, 256, 128, 0, 256);
    wprep_k<<<(256 * 128 + 255) / 256, 256, 0, stream>>>(Wv,  Wkv_s, 256, 128, 128, 256);
    wprep_k<<<(128 * 128 + 255) / 256, 256, 0, stream>>>(Wn1, Wn1_s, 128, 128, 0, 128);
    wprep_k<<<(128 * 128 + 255) / 256, 256, 0, stream>>>(Wn2, Wn2_s, 128, 128, 0, 128);
    wprep_k<<<(384 * 128 + 255) / 256, 256, 0, stream>>>(We1, We1_s, 384, 128, 0, 384);
    wprep_k<<<(128 * 128 + 255) / 256, 256, 0, stream>>>(We2, We2_s, 128, 128, 0, 128);
    hipMemcpyAsync(b_kv,       bk, 128 * 4, hipMemcpyDeviceToDevice, stream);
    hipMemcpyAsync(b_kv + 128, bv, 128 * 4, hipMemcpyDeviceToDevice, stream);

    // activations -> bf16 (one-time; same rounding as the old inline f2bf path)
    cvt_k<<<(NN * HH / 8 + 255) / 256, 256, 0, stream>>>(h, hbf, (long)NN * HH / 8);
    cvt_k<<<(EE * HH / 8 + 255) / 256, 256, 0, stream>>>(e, ebf, (long)EE * HH / 8);

    // CSR build
    hipMemsetAsync(cursor, 0, (size_t)NN * 4, stream);
    hist_k<<<(EE + 255) / 256, 256, 0, stream>>>(dst, cursor);
    blocksum_k<<<nb, 256, 0, stream>>>(cursor, bsum);
    scanb_k<<<1, 256, 0, stream>>>(bsum, nb);
    offsets_k<<<nb, 256, 0, stream>>>(cursor, bsum, offsets, cursor);
    fill_k<<<(EE + 255) / 256, 256, 0, stream>>>(dst, cursor, eids);

    // Q = h @ Wq + bq  (f32 out)  [128 rows x 128 cols per block]
    mm3_k<1, 4, 4, 0><<<(NN + 127) / 128, 512, 0, stream>>>(
        hbf, nullptr, nullptr, nullptr, nullptr, nullptr,
        Wq_s, bq, NN, Q, nullptr, 128, nullptr, nullptr, nullptr);

    // K|V = [h[src], e] @ [Wk|Wv] + [bk|bv]  (bf16 interleaved [E][256])
    // 64 rows x 256 cols per block (8 col-waves share the staged A rows -> e once)
    mm3_k<2, 8, 4, 2><<<EE / 64, 512, 0, stream>>>(
        hbf, src, ebf, nullptr, nullptr, nullptr,
        Wkv_s, b_kv, EE, nullptr, (unsigned short*)KV, 256, nullptr, nullptr, nullptr);

    score_k<<<EE / 2, 256, 0, stream>>>(Q, KV, dst, sbuf);
    agg_k<<<(NN + 3) / 4, 256, 0, stream>>>(KV, sbuf, offsets, eids, hagg);

    // node MLP + residual + LN -> h_out
    mm3_k<1, 4, 4, 4><<<(NN + 127) / 128, 512, 0, stream>>>(
        hagg, nullptr, nullptr, nullptr, nullptr, nullptr,
        Wn1_s, bn1, NN, nullptr, tnode, 128, nullptr, nullptr, nullptr);
    mm3_k<1, 4, 4, 3><<<(NN + 127) / 128, 512, 0, stream>>>(
        tnode, nullptr, nullptr, nullptr, nullptr, nullptr,
        Wn2_s, bn2, NN, h_out, nullptr, 128, h, gh, bh);

    // h_out -> bf16 for the edge-MLP gathers
    cvt_k<<<(NN * HH / 8 + 255) / 256, 256, 0, stream>>>(h_out, hobf, (long)NN * HH / 8);

    // edge MLP on [h_out[src], h_out[dst], e] + residual + LN -> e_out
    mm3_k<3, 4, 2, 4><<<EE / 64, 512, 0, stream>>>(
        hobf, src, hobf, dst, ebf, nullptr,
        We1_s, be1, EE, nullptr, t_edge, 128, nullptr, nullptr, nullptr);
    mm3_k<1, 4, 4, 3><<<EE / 128, 512, 0, stream>>>(
        t_edge, nullptr, nullptr, nullptr, nullptr, nullptr,
        We2_s, be2, EE, e_out, nullptr, 128, e, ge, be_);
}

// Round 6
// 1576.409 us; speedup vs baseline: 1.2769x; 1.1090x over previous
//
#include <hip/hip_runtime.h>
#include <hip/hip_bf16.h>

#define NN 50000
#define EE 800000
#define HH 128

typedef __attribute__((ext_vector_type(8))) short bf16x8;
typedef __attribute__((ext_vector_type(4))) float f32x4;

__device__ inline unsigned short f2bf(float f) {
    union { float f; unsigned u; } v; v.f = f;
    unsigned r = v.u + 0x7FFF + ((v.u >> 16) & 1);
    return (unsigned short)(r >> 16);
}

// ---------------- CSR build (edges grouped by dst) ----------------
__global__ __launch_bounds__(256) void hist_k(const int* __restrict__ dst, int* __restrict__ cnt) {
    int i = blockIdx.x * 256 + threadIdx.x;
    if (i < EE) atomicAdd(&cnt[dst[i]], 1);
}

__global__ __launch_bounds__(256) void blocksum_k(const int* __restrict__ cnt, int* __restrict__ bsum) {
    __shared__ int sm[256];
    int i = blockIdx.x * 256 + threadIdx.x;
    sm[threadIdx.x] = (i < NN) ? cnt[i] : 0;
    __syncthreads();
    for (int s = 128; s > 0; s >>= 1) {
        if (threadIdx.x < s) sm[threadIdx.x] += sm[threadIdx.x + s];
        __syncthreads();
    }
    if (threadIdx.x == 0) bsum[blockIdx.x] = sm[0];
}

__global__ __launch_bounds__(256) void scanb_k(int* __restrict__ bsum, int nb) {
    __shared__ int sm[256];
    int t = threadIdx.x;
    sm[t] = (t < nb) ? bsum[t] : 0;
    __syncthreads();
    for (int d = 1; d < 256; d <<= 1) {
        int v = (t >= d) ? sm[t - d] : 0;
        __syncthreads();
        sm[t] += v;
        __syncthreads();
    }
    if (t < nb) bsum[t] = sm[t];
}

__global__ __launch_bounds__(256) void offsets_k(const int* __restrict__ cnt, const int* __restrict__ bsum,
                                                 int* __restrict__ offsets, int* __restrict__ cursor) {
    __shared__ int sm[256];
    int b = blockIdx.x, t = threadIdx.x;
    int i = b * 256 + t;
    int c = (i < NN) ? cnt[i] : 0;
    sm[t] = c;
    __syncthreads();
    for (int d = 1; d < 256; d <<= 1) {
        int v = (t >= d) ? sm[t - d] : 0;
        __syncthreads();
        sm[t] += v;
        __syncthreads();
    }
    int incl = sm[t];
    int base = (b == 0) ? 0 : bsum[b - 1];
    int off = base + incl - c;
    if (i < NN) { offsets[i] = off; cursor[i] = off; }
    if (i == NN - 1) offsets[NN] = off + c;
}

__global__ __launch_bounds__(256) void fill_k(const int* __restrict__ dst, int* __restrict__ cursor,
                                              int* __restrict__ eids) {
    int i = blockIdx.x * 256 + threadIdx.x;
    if (i < EE) { int p = atomicAdd(&cursor[dst[i]], 1); eids[p] = i; }
}

// ---------------- weight prep: W[fi][fo] f32 -> W_t[n][k] bf16 (plain transpose) ----------------
__global__ __launch_bounds__(256) void wprep_k(const float* __restrict__ W, unsigned short* __restrict__ out,
                                               int fi, int fo, int n_off, int out_ld) {
    int i = blockIdx.x * 256 + threadIdx.x;
    if (i >= fi * fo) return;
    int n = i / fi, k = i - n * fi;
    out[(size_t)(n_off + n) * out_ld + k] = f2bf(W[(size_t)k * fo + n]);
}

// ---------------- f32 -> bf16 bulk convert (8 elems/thread) ----------------
__global__ __launch_bounds__(256) void cvt_k(const float* __restrict__ in, unsigned short* __restrict__ out,
                                             long n8) {
    long i = (long)blockIdx.x * 256 + threadIdx.x;
    if (i >= n8) return;
    const float4* p = (const float4*)in + i * 2;
    float4 a = p[0], b = p[1];
    bf16x8 o = {(short)f2bf(a.x), (short)f2bf(a.y), (short)f2bf(a.z), (short)f2bf(a.w),
                (short)f2bf(b.x), (short)f2bf(b.y), (short)f2bf(b.z), (short)f2bf(b.w)};
    *((bf16x8*)out + i) = o;
}

// ---------------- chunked MFMA gather-GEMM: A in LDS (per 128-k chunk), B in regs ----------------
// (structure as R5; RT raised where it pays: per-chunk compute must exceed the
//  stage-barrier drain for cross-block covering at 2 blocks/CU)
// MODE: 0 f32, 1 f32+relu, 2 bf16, 4 bf16+relu, 3 relu+resid+LayerNorm(128) f32
template <int G, int NCW, int RT, int MODE>
__global__ __launch_bounds__(512, 2) void mm3_k(
    const unsigned short* __restrict__ A0, const int* __restrict__ idx0,
    const unsigned short* __restrict__ A1, const int* __restrict__ idx1,
    const unsigned short* __restrict__ A2, const int* __restrict__ idx2,
    const unsigned short* __restrict__ Wt, const float* __restrict__ bias,
    int M,
    float* __restrict__ Cf, unsigned short* __restrict__ Cb, int out_ld,
    const float* __restrict__ resid, const float* __restrict__ gamma, const float* __restrict__ beta)
{
    constexpr int RW = 8 / NCW;
    constexpr int ROWS = RW * RT * 16;
    constexpr int Ktot = G * 128;
    constexpr int SI = ROWS / 32;            // global_load_lds issues per thread per chunk
    __shared__ unsigned short Asl[ROWS * 128];
    __shared__ float lnbuf[(MODE == 3) ? RT * 32 * 8 : 8];

    const int t = threadIdx.x;
    const int wid = t >> 6, lane = t & 63;
    const int lr = lane & 15, lk = lane >> 4;
    const int colw = (NCW == 8) ? wid : (wid & 3);
    const int roww = (NCW == 8) ? 0 : (wid >> 2);
    const int col0 = colw << 5;
    const int tbase = blockIdx.x * ROWS;

    const unsigned short* As[3] = {A0, A1, A2};
    const int* igs[3] = {idx0, idx1, idx2};

    f32x4 acc[RT][2];
    #pragma unroll
    for (int tt = 0; tt < RT; ++tt) { acc[tt][0] = (f32x4){0,0,0,0}; acc[tt][1] = (f32x4){0,0,0,0}; }

    for (int g = 0; g < G; ++g) {
        if (g) __syncthreads();   // all ds_reads of chunk g-1 done before overwrite

        // stage A_g: LDS[row][c16] = Ag[rid(row)][ (c16 ^ (row&7)) * 8 .. +8 ]
        const unsigned short* Ag = As[g];
        const int* ig = igs[g];
        #pragma unroll
        for (int i = 0; i < SI; ++i) {
            int rl = ((i * 8 + wid) << 2) + (lane >> 4);     // block-local row
            int gr = tbase + rl; if (gr >= M) gr = M - 1;
            int rid = ig ? ig[gr] : gr;
            const unsigned short* src = Ag + (size_t)rid * HH + (((lane & 15) ^ (rl & 7)) << 3);
            unsigned short* dst = &Asl[(i * 8 + wid) << 9];
            __builtin_amdgcn_global_load_lds((const __attribute__((address_space(1))) void*)src,
                                             (__attribute__((address_space(3))) void*)dst, 16, 0, 0);
        }

        // B chunk: 4 k-steps x 2 col-fragments = 32 VGPR, loaded from L2
        bf16x8 b[4][2];
        #pragma unroll
        for (int s = 0; s < 4; ++s)
            #pragma unroll
            for (int c = 0; c < 2; ++c)
                b[s][c] = *(const bf16x8*)(Wt + (size_t)(col0 + (c << 4) + lr) * Ktot + (g << 7) + (s << 5) + (lk << 3));

        __syncthreads();

        #pragma unroll
        for (int tt = 0; tt < RT; ++tt) {
            const int tl = (tt * RW + roww) << 4;
            bf16x8 a[4];
            #pragma unroll
            for (int s = 0; s < 4; ++s) {
                const int c16 = ((s << 2) + lk) ^ (lr & 7);
                a[s] = *(const bf16x8*)&Asl[((tl + lr) << 7) + (c16 << 3)];
            }
            #pragma unroll
            for (int s = 0; s < 4; ++s) {
                acc[tt][0] = __builtin_amdgcn_mfma_f32_16x16x32_bf16(a[s], b[s][0], acc[tt][0], 0, 0, 0);
                acc[tt][1] = __builtin_amdgcn_mfma_f32_16x16x32_bf16(a[s], b[s][1], acc[tt][1], 0, 0, 0);
            }
        }
    }

    // ---------------- epilogue ----------------
    float bias2[2] = {bias[col0 + lr], bias[col0 + 16 + lr]};

    if (MODE == 3) {
        float g2[2] = {gamma[col0 + lr], gamma[col0 + 16 + lr]};
        float be2[2] = {beta[col0 + lr], beta[col0 + 16 + lr]};
        #pragma unroll
        for (int tt = 0; tt < RT; ++tt) {
            #pragma unroll
            for (int rr = 0; rr < 4; ++rr) {
                int row = tbase + ((tt * RW + roww) << 4) + (lk << 2) + rr;
                int rowc = (row < M) ? row : M - 1;
                float sum = 0.f, sq = 0.f;
                #pragma unroll
                for (int c = 0; c < 2; ++c) {
                    float v = fmaxf(acc[tt][c][rr] + bias2[c], 0.f);
                    v += resid[(size_t)rowc * HH + col0 + (c << 4) + lr];
                    acc[tt][c][rr] = v;
                    sum += v; sq += v * v;
                }
                sum += __shfl_xor(sum, 1); sq += __shfl_xor(sq, 1);
                sum += __shfl_xor(sum, 2); sq += __shfl_xor(sq, 2);
                sum += __shfl_xor(sum, 4); sq += __shfl_xor(sq, 4);
                sum += __shfl_xor(sum, 8); sq += __shfl_xor(sq, 8);
                if (lr == 0) {
                    int rls = (roww << 4) + (lk << 2) + rr;
                    lnbuf[((tt * 32 + rls) << 3) + (colw << 1) + 0] = sum;
                    lnbuf[((tt * 32 + rls) << 3) + (colw << 1) + 1] = sq;
                }
            }
        }
        __syncthreads();
        #pragma unroll
        for (int tt = 0; tt < RT; ++tt) {
            #pragma unroll
            for (int rr = 0; rr < 4; ++rr) {
                int rls = (roww << 4) + (lk << 2) + rr;
                float s4 = 0.f, q4 = 0.f;
                #pragma unroll
                for (int cw = 0; cw < 4; ++cw) {
                    s4 += lnbuf[((tt * 32 + rls) << 3) + (cw << 1) + 0];
                    q4 += lnbuf[((tt * 32 + rls) << 3) + (cw << 1) + 1];
                }
                const float mean = s4 * (1.f / 128.f);
                const float var = q4 * (1.f / 128.f) - mean * mean;
                const float rs = rsqrtf(var + 1e-5f);
                int row = tbase + ((tt * RW + roww) << 4) + (lk << 2) + rr;
                if (row < M) {
                    #pragma unroll
                    for (int c = 0; c < 2; ++c)
                        Cf[(size_t)row * out_ld + col0 + (c << 4) + lr] =
                            (acc[tt][c][rr] - mean) * rs * g2[c] + be2[c];
                }
            }
        }
    } else {
        #pragma unroll
        for (int tt = 0; tt < RT; ++tt) {
            #pragma unroll
            for (int rr = 0; rr < 4; ++rr) {
                int row = tbase + ((tt * RW + roww) << 4) + (lk << 2) + rr;
                if (row >= M) continue;
                #pragma unroll
                for (int c = 0; c < 2; ++c) {
                    float v = acc[tt][c][rr] + bias2[c];
                    if (MODE == 1 || MODE == 4) v = fmaxf(v, 0.f);
                    size_t o = (size_t)row * out_ld + col0 + (c << 4) + lr;
                    if (MODE == 0 || MODE == 1) Cf[o] = v;
                    else Cb[o] = f2bf(v);
                }
            }
        }
    }
}

// ---------------- fused K|V GEMM + attention score ----------------
// Per block: 64 edges. 8 col-waves x 32 cols over [Wk|Wv] (K = cols 0..127 =
// heads 0..3 -> col-waves 0..3; V = cols 128..255 -> col-waves 4..7).
// K is NEVER materialized: col-wave h computes s[e,h] = <K[e,h,:], Q[dst[e],h,:]>
// / sqrt(32) from its accumulators (f32) + gathered Q rows (L3-resident).
// V written as bf16 [E][128]. Saves 204MB K write + 204MB K read + score_k.
template <int RT>
__global__ __launch_bounds__(512, 2) void kv_k(
    const unsigned short* __restrict__ hbf, const int* __restrict__ src,
    const unsigned short* __restrict__ ebf,
    const unsigned short* __restrict__ Wt, const float* __restrict__ bias,
    const float* __restrict__ Q, const int* __restrict__ dst,
    int M, unsigned short* __restrict__ V, float* __restrict__ sbuf)
{
    constexpr int ROWS = RT * 16;
    constexpr int Ktot = 256;
    constexpr int SI = ROWS / 32;
    __shared__ unsigned short Asl[ROWS * 128];

    const int t = threadIdx.x;
    const int wid = t >> 6, lane = t & 63;
    const int lr = lane & 15, lk = lane >> 4;
    const int colw = wid;
    const int col0 = colw << 5;
    const int tbase = blockIdx.x * ROWS;

    f32x4 acc[RT][2];
    #pragma unroll
    for (int tt = 0; tt < RT; ++tt) { acc[tt][0] = (f32x4){0,0,0,0}; acc[tt][1] = (f32x4){0,0,0,0}; }

    for (int g = 0; g < 2; ++g) {
        if (g) __syncthreads();
        const unsigned short* Ag = g ? ebf : hbf;
        const int* ig = g ? nullptr : src;
        #pragma unroll
        for (int i = 0; i < SI; ++i) {
            int rl = ((i * 8 + wid) << 2) + (lane >> 4);
            int gr = tbase + rl; if (gr >= M) gr = M - 1;
            int rid = ig ? ig[gr] : gr;
            const unsigned short* srcp = Ag + (size_t)rid * HH + (((lane & 15) ^ (rl & 7)) << 3);
            unsigned short* dstp = &Asl[(i * 8 + wid) << 9];
            __builtin_amdgcn_global_load_lds((const __attribute__((address_space(1))) void*)srcp,
                                             (__attribute__((address_space(3))) void*)dstp, 16, 0, 0);
        }

        bf16x8 b[4][2];
        #pragma unroll
        for (int s = 0; s < 4; ++s)
            #pragma unroll
            for (int c = 0; c < 2; ++c)
                b[s][c] = *(const bf16x8*)(Wt + (size_t)(col0 + (c << 4) + lr) * Ktot + (g << 7) + (s << 5) + (lk << 3));

        __syncthreads();

        #pragma unroll
        for (int tt = 0; tt < RT; ++tt) {
            const int tl = tt << 4;
            bf16x8 a[4];
            #pragma unroll
            for (int s = 0; s < 4; ++s) {
                const int c16 = ((s << 2) + lk) ^ (lr & 7);
                a[s] = *(const bf16x8*)&Asl[((tl + lr) << 7) + (c16 << 3)];
            }
            #pragma unroll
            for (int s = 0; s < 4; ++s) {
                acc[tt][0] = __builtin_amdgcn_mfma_f32_16x16x32_bf16(a[s], b[s][0], acc[tt][0], 0, 0, 0);
                acc[tt][1] = __builtin_amdgcn_mfma_f32_16x16x32_bf16(a[s], b[s][1], acc[tt][1], 0, 0, 0);
            }
        }
    }

    float bias2[2] = {bias[col0 + lr], bias[col0 + 16 + lr]};

    if (colw < 4) {
        // score epilogue: s[row, head=colw] = <acc+bk, Q[dst[row], head cols]> / sqrt(32)
        #pragma unroll
        for (int tt = 0; tt < RT; ++tt) {
            #pragma unroll
            for (int rr = 0; rr < 4; ++rr) {
                int row = tbase + (tt << 4) + (lk << 2) + rr;
                int rowc = (row < M) ? row : M - 1;
                int d = dst[rowc];
                float q0 = Q[(size_t)d * HH + col0 + lr];
                float q1 = Q[(size_t)d * HH + col0 + 16 + lr];
                float p = (acc[tt][0][rr] + bias2[0]) * q0 + (acc[tt][1][rr] + bias2[1]) * q1;
                p += __shfl_xor(p, 1); p += __shfl_xor(p, 2);
                p += __shfl_xor(p, 4); p += __shfl_xor(p, 8);
                if (lr == 0 && row < M)
                    sbuf[(size_t)row * 4 + colw] = p * 0.17677669529663687f;
            }
        }
    } else {
        // V epilogue: bf16 [E][128]
        #pragma unroll
        for (int tt = 0; tt < RT; ++tt) {
            #pragma unroll
            for (int rr = 0; rr < 4; ++rr) {
                int row = tbase + (tt << 4) + (lk << 2) + rr;
                if (row >= M) continue;
                #pragma unroll
                for (int c = 0; c < 2; ++c)
                    V[(size_t)row * HH + (col0 - 128) + (c << 4) + lr] = f2bf(acc[tt][c][rr] + bias2[c]);
            }
        }
    }
}

// ---------------- per-node online-softmax aggregation (one wave per node) ----------------
__global__ __launch_bounds__(256) void agg_k(const __hip_bfloat16* __restrict__ Vb,
                                             const float* __restrict__ s,
                                             const int* __restrict__ offsets,
                                             const int* __restrict__ eids,
                                             unsigned short* __restrict__ hagg)
{
    const int t = threadIdx.x;
    const int n = blockIdx.x * 4 + (t >> 6);
    if (n >= NN) return;
    const int lane = t & 63;
    const int c0 = lane, c1 = lane + 64;
    const int h0 = lane >> 5, h1 = h0 + 2;
    const int o0 = offsets[n], o1 = offsets[n + 1];
    float m0 = -1e30f, m1 = -1e30f, d0 = 0.f, d1 = 0.f, a0 = 0.f, a1 = 0.f;
    for (int j = o0; j < o1; ++j) {
        const int e = eids[j];
        const float s0 = s[(size_t)e * 4 + h0];
        const float s1 = s[(size_t)e * 4 + h1];
        const float v0 = __bfloat162float(Vb[(size_t)e * HH + c0]);
        const float v1 = __bfloat162float(Vb[(size_t)e * HH + c1]);
        float nm = fmaxf(m0, s0);
        float sc = __expf(m0 - nm);
        float w  = __expf(s0 - nm);
        d0 = d0 * sc + w; a0 = a0 * sc + w * v0; m0 = nm;
        nm = fmaxf(m1, s1);
        sc = __expf(m1 - nm);
        w  = __expf(s1 - nm);
        d1 = d1 * sc + w; a1 = a1 * sc + w * v1; m1 = nm;
    }
    const bool any = (o1 > o0);
    hagg[(size_t)n * HH + c0] = any ? f2bf(a0 / d0) : 0;
    hagg[(size_t)n * HH + c1] = any ? f2bf(a1 / d1) : 0;
}

extern "C" void kernel_launch(void* const* d_in, const int* in_sizes, int n_in,
                              void* d_out, int out_size, void* d_ws, size_t ws_size,
                              hipStream_t stream)
{
    const float* h   = (const float*)d_in[0];
    const float* e   = (const float*)d_in[1];
    const int*   src = (const int*)d_in[2];
    const int*   dst = (const int*)d_in[3];
    const float* Wq  = (const float*)d_in[4];
    const float* bq  = (const float*)d_in[5];
    const float* Wk  = (const float*)d_in[6];
    const float* bk  = (const float*)d_in[7];
    const float* Wv  = (const float*)d_in[8];
    const float* bv  = (const float*)d_in[9];
    const float* Wn1 = (const float*)d_in[10];
    const float* bn1 = (const float*)d_in[11];
    const float* Wn2 = (const float*)d_in[12];
    const float* bn2 = (const float*)d_in[13];
    const float* We1 = (const float*)d_in[14];
    const float* be1 = (const float*)d_in[15];
    const float* We2 = (const float*)d_in[16];
    const float* be2 = (const float*)d_in[17];
    const float* gh  = (const float*)d_in[18];
    const float* bh  = (const float*)d_in[19];
    const float* ge  = (const float*)d_in[20];
    const float* be_ = (const float*)d_in[21];
    (void)in_sizes; (void)n_in; (void)out_size; (void)ws_size;

    float* h_out = (float*)d_out;
    float* e_out = (float*)d_out + (size_t)NN * HH;

    char* ws = (char*)d_ws;
    size_t off = 0;
    auto carve = [&](size_t bytes) { void* p = ws + off; off += (bytes + 255) & ~(size_t)255; return p; };
    unsigned short* Vbuf = (unsigned short*)carve((size_t)EE * HH * 2); // V bf16 [E][128]; reused as t_edge after agg
    unsigned short* t_edge = Vbuf;
    unsigned short* ebf = (unsigned short*)carve((size_t)EE * HH * 2); // e in bf16
    float* Q      = (float*)carve((size_t)NN * HH * 4);                // reused as tnode (bf16) after kv
    unsigned short* tnode = (unsigned short*)Q;
    float* sbuf   = (float*)carve((size_t)EE * 4 * 4);
    unsigned short* hagg = (unsigned short*)carve((size_t)NN * HH * 2); // reused as hobf after Wn1
    unsigned short* hobf = hagg;
    unsigned short* hbf  = (unsigned short*)carve((size_t)NN * HH * 2);
    int* cursor   = (int*)carve((size_t)NN * 4);
    int* offsets  = (int*)carve((size_t)(NN + 1) * 4);
    int* bsum     = (int*)carve(256 * 4);
    int* eids     = (int*)carve((size_t)EE * 4);
    unsigned short* Wq_s  = (unsigned short*)carve(128 * 128 * 2);
    unsigned short* Wkv_s = (unsigned short*)carve(256 * 256 * 2);
    unsigned short* Wn1_s = (unsigned short*)carve(128 * 128 * 2);
    unsigned short* Wn2_s = (unsigned short*)carve(128 * 128 * 2);
    unsigned short* We1_s = (unsigned short*)carve(128 * 384 * 2);
    unsigned short* We2_s = (unsigned short*)carve(128 * 128 * 2);
    float* b_kv   = (float*)carve(256 * 4);

    const int nb = (NN + 255) / 256;

    // weight prep (bf16 transpose) + combined KV bias
    wprep_k<<<(128 * 128 + 255) / 256, 256, 0, stream>>>(Wq,  Wq_s,  128, 128, 0, 128);
    wprep_k<<<(256 * 128 + 255) / 256, 256, 0, stream>>>(Wk,  Wkv_s, 256, 128, 0, 256);
    wprep_k<<<(256 * 128 + 255) / 256, 256, 0, stream>>>(Wv,  Wkv_s, 256, 128, 128, 256);
    wprep_k<<<(128 * 128 + 255) / 256, 256, 0, stream>>>(Wn1, Wn1_s, 128, 128, 0, 128);
    wprep_k<<<(128 * 128 + 255) / 256, 256, 0, stream>>>(Wn2, Wn2_s, 128, 128, 0, 128);
    wprep_k<<<(384 * 128 + 255) / 256, 256, 0, stream>>>(We1, We1_s, 384, 128, 0, 384);
    wprep_k<<<(128 * 128 + 255) / 256, 256, 0, stream>>>(We2, We2_s, 128, 128, 0, 128);
    hipMemcpyAsync(b_kv,       bk, 128 * 4, hipMemcpyDeviceToDevice, stream);
    hipMemcpyAsync(b_kv + 128, bv, 128 * 4, hipMemcpyDeviceToDevice, stream);

    // activations -> bf16 (one-time; same rounding as the old inline f2bf path)
    cvt_k<<<(NN * HH / 8 + 255) / 256, 256, 0, stream>>>(h, hbf, (long)NN * HH / 8);
    cvt_k<<<(EE * HH / 8 + 255) / 256, 256, 0, stream>>>(e, ebf, (long)EE * HH / 8);

    // CSR build
    hipMemsetAsync(cursor, 0, (size_t)NN * 4, stream);
    hist_k<<<(EE + 255) / 256, 256, 0, stream>>>(dst, cursor);
    blocksum_k<<<nb, 256, 0, stream>>>(cursor, bsum);
    scanb_k<<<1, 256, 0, stream>>>(bsum, nb);
    offsets_k<<<nb, 256, 0, stream>>>(cursor, bsum, offsets, cursor);
    fill_k<<<(EE + 255) / 256, 256, 0, stream>>>(dst, cursor, eids);

    // Q = h @ Wq + bq  (f32 out)  [128 rows x 128 cols per block]
    mm3_k<1, 4, 4, 0><<<(NN + 127) / 128, 512, 0, stream>>>(
        hbf, nullptr, nullptr, nullptr, nullptr, nullptr,
        Wq_s, bq, NN, Q, nullptr, 128, nullptr, nullptr, nullptr);

    // fused K|V GEMM + score: V bf16 [E][128] + s[E][4]; K never materialized
    kv_k<4><<<EE / 64, 512, 0, stream>>>(
        hbf, src, ebf, Wkv_s, b_kv, Q, dst, EE, Vbuf, sbuf);

    agg_k<<<(NN + 3) / 4, 256, 0, stream>>>((const __hip_bfloat16*)Vbuf, sbuf, offsets, eids, hagg);

    // node MLP + residual + LN -> h_out
    mm3_k<1, 4, 4, 4><<<(NN + 127) / 128, 512, 0, stream>>>(
        hagg, nullptr, nullptr, nullptr, nullptr, nullptr,
        Wn1_s, bn1, NN, nullptr, tnode, 128, nullptr, nullptr, nullptr);
    mm3_k<1, 4, 4, 3><<<(NN + 127) / 128, 512, 0, stream>>>(
        tnode, nullptr, nullptr, nullptr, nullptr, nullptr,
        Wn2_s, bn2, NN, h_out, nullptr, 128, h, gh, bh);

    // h_out -> bf16 for the edge-MLP gathers
    cvt_k<<<(NN * HH / 8 + 255) / 256, 256, 0, stream>>>(h_out, hobf, (long)NN * HH / 8);

    // edge MLP on [h_out[src], h_out[dst], e] + residual + LN -> e_out
    mm3_k<3, 4, 4, 4><<<EE / 128, 512, 0, stream>>>(
        hobf, src, hobf, dst, ebf, nullptr,
        We1_s, be1, EE, nullptr, t_edge, 128, nullptr, nullptr, nullptr);
    mm3_k<1, 4, 4, 3><<<EE / 128, 512, 0, stream>>>(
        t_edge, nullptr, nullptr, nullptr, nullptr, nullptr,
        We2_s, be2, EE, e_out, nullptr, 128, e, ge, be_);
}

// Round 7
// 1401.691 us; speedup vs baseline: 1.4361x; 1.1246x over previous
//
#include <hip/hip_runtime.h>
#include <hip/hip_bf16.h>

#define NN 50000
#define EE 800000
#define HH 128

typedef __attribute__((ext_vector_type(8))) short bf16x8;
typedef __attribute__((ext_vector_type(4))) float f32x4;

__device__ inline unsigned short f2bf(float f) {
    union { float f; unsigned u; } v; v.f = f;
    unsigned r = v.u + 0x7FFF + ((v.u >> 16) & 1);
    return (unsigned short)(r >> 16);
}

// ---------------- CSR build (edges grouped by dst) ----------------
__global__ __launch_bounds__(256) void hist_k(const int* __restrict__ dst, int* __restrict__ cnt) {
    int i = blockIdx.x * 256 + threadIdx.x;
    if (i < EE) atomicAdd(&cnt[dst[i]], 1);
}

__global__ __launch_bounds__(256) void blocksum_k(const int* __restrict__ cnt, int* __restrict__ bsum) {
    __shared__ int sm[256];
    int i = blockIdx.x * 256 + threadIdx.x;
    sm[threadIdx.x] = (i < NN) ? cnt[i] : 0;
    __syncthreads();
    for (int s = 128; s > 0; s >>= 1) {
        if (threadIdx.x < s) sm[threadIdx.x] += sm[threadIdx.x + s];
        __syncthreads();
    }
    if (threadIdx.x == 0) bsum[blockIdx.x] = sm[0];
}

__global__ __launch_bounds__(256) void scanb_k(int* __restrict__ bsum, int nb) {
    __shared__ int sm[256];
    int t = threadIdx.x;
    sm[t] = (t < nb) ? bsum[t] : 0;
    __syncthreads();
    for (int d = 1; d < 256; d <<= 1) {
        int v = (t >= d) ? sm[t - d] : 0;
        __syncthreads();
        sm[t] += v;
        __syncthreads();
    }
    if (t < nb) bsum[t] = sm[t];
}

__global__ __launch_bounds__(256) void offsets_k(const int* __restrict__ cnt, const int* __restrict__ bsum,
                                                 int* __restrict__ offsets, int* __restrict__ cursor) {
    __shared__ int sm[256];
    int b = blockIdx.x, t = threadIdx.x;
    int i = b * 256 + t;
    int c = (i < NN) ? cnt[i] : 0;
    sm[t] = c;
    __syncthreads();
    for (int d = 1; d < 256; d <<= 1) {
        int v = (t >= d) ? sm[t - d] : 0;
        __syncthreads();
        sm[t] += v;
        __syncthreads();
    }
    int incl = sm[t];
    int base = (b == 0) ? 0 : bsum[b - 1];
    int off = base + incl - c;
    if (i < NN) { offsets[i] = off; cursor[i] = off; }
    if (i == NN - 1) offsets[NN] = off + c;
}

__global__ __launch_bounds__(256) void fill_k(const int* __restrict__ dst, int* __restrict__ cursor,
                                              int* __restrict__ eids) {
    int i = blockIdx.x * 256 + threadIdx.x;
    if (i < EE) { int p = atomicAdd(&cursor[dst[i]], 1); eids[p] = i; }
}

// ---------------- weight prep: W[fi][fo] f32 -> W_t[n][k] bf16 (plain transpose) ----------------
__global__ __launch_bounds__(256) void wprep_k(const float* __restrict__ W, unsigned short* __restrict__ out,
                                               int fi, int fo, int n_off, int out_ld) {
    int i = blockIdx.x * 256 + threadIdx.x;
    if (i >= fi * fo) return;
    int n = i / fi, k = i - n * fi;
    out[(size_t)(n_off + n) * out_ld + k] = f2bf(W[(size_t)k * fo + n]);
}

// ---------------- f32 -> bf16 bulk convert (8 elems/thread) ----------------
__global__ __launch_bounds__(256) void cvt_k(const float* __restrict__ in, unsigned short* __restrict__ out,
                                             long n8) {
    long i = (long)blockIdx.x * 256 + threadIdx.x;
    if (i >= n8) return;
    const float4* p = (const float4*)in + i * 2;
    float4 a = p[0], b = p[1];
    bf16x8 o = {(short)f2bf(a.x), (short)f2bf(a.y), (short)f2bf(a.z), (short)f2bf(a.w),
                (short)f2bf(b.x), (short)f2bf(b.y), (short)f2bf(b.z), (short)f2bf(b.w)};
    *((bf16x8*)out + i) = o;
}

// ---------------- single-barrier MFMA gather-GEMM: whole A panel in LDS, B in regs ----------------
// C[M, NCW*32] = act( concat_g Ag[idx_g(row)] @ W + bias ), A operands bf16 [*][128].
// 8 waves = RW(=8/NCW) row-waves x NCW col-waves; per-wave tile 16 rows x 32 cols,
// RT tiles per row-wave; ROWS = RW*RT*16 per block.
// KEY CHANGE vs R5/R6 (which pinned at ~8% MfmaUtil): stage ALL G chunks of the
// A panel (<=48KB) with back-to-back global_load_lds, then take ONE __syncthreads
// (one vmcnt(0) drain per block instead of G), then the entire K-loop runs
// barrier-free from LDS: compiler pipelines ds_read->MFMA with counted lgkmcnt,
// and ~3 resident blocks/CU cover each other's single stage drain.
// XOR-swizzled stage source (both-sides swizzle) keeps ds_read_b128 conflict-low.
// MODE: 0 f32, 1 f32+relu, 2 bf16, 4 bf16+relu, 3 relu+resid+LayerNorm(128) f32
template <int G, int NCW, int RT, int MODE>
__global__ __launch_bounds__(512, 2) void mm4_k(
    const unsigned short* __restrict__ A0, const int* __restrict__ idx0,
    const unsigned short* __restrict__ A1, const int* __restrict__ idx1,
    const unsigned short* __restrict__ A2, const int* __restrict__ idx2,
    const unsigned short* __restrict__ Wt, const float* __restrict__ bias,
    int M,
    float* __restrict__ Cf, unsigned short* __restrict__ Cb, int out_ld,
    const float* __restrict__ resid, const float* __restrict__ gamma, const float* __restrict__ beta)
{
    constexpr int RW = 8 / NCW;
    constexpr int ROWS = RW * RT * 16;
    constexpr int Ktot = G * 128;
    constexpr int SI = ROWS / 32;            // global_load_lds issues per thread per chunk
    __shared__ unsigned short Asl[G * ROWS * 128];
    __shared__ float lnbuf[(MODE == 3) ? RT * 32 * 8 : 8];

    const int t = threadIdx.x;
    const int wid = t >> 6, lane = t & 63;
    const int lr = lane & 15, lk = lane >> 4;
    const int colw = (NCW == 8) ? wid : (wid & 3);
    const int roww = (NCW == 8) ? 0 : (wid >> 2);
    const int col0 = colw << 5;
    const int tbase = blockIdx.x * ROWS;

    const unsigned short* As[3] = {A0, A1, A2};
    const int* igs[3] = {idx0, idx1, idx2};

    // stage ALL G chunks: LDS[g][row][c16] = Ag[rid(row)][ c16 ^ (row&7) ]  (bf16x8 units)
    #pragma unroll
    for (int g = 0; g < G; ++g) {
        const unsigned short* Ag = As[g];
        const int* ig = igs[g];
        #pragma unroll
        for (int i = 0; i < SI; ++i) {
            int rl = ((i * 8 + wid) << 2) + (lane >> 4);     // block-local row
            int gr = tbase + rl; if (gr >= M) gr = M - 1;
            int rid = ig ? ig[gr] : gr;
            const unsigned short* src = Ag + (size_t)rid * HH + (((lane & 15) ^ (rl & 7)) << 3);
            unsigned short* dst = &Asl[(g * ROWS + ((i * 8 + wid) << 2)) << 7];
            __builtin_amdgcn_global_load_lds((const __attribute__((address_space(1))) void*)src,
                                             (__attribute__((address_space(3))) void*)dst, 16, 0, 0);
        }
    }

    f32x4 acc[RT][2];
    #pragma unroll
    for (int tt = 0; tt < RT; ++tt) { acc[tt][0] = (f32x4){0,0,0,0}; acc[tt][1] = (f32x4){0,0,0,0}; }

    __syncthreads();   // the ONLY stage barrier in the kernel

    #pragma unroll
    for (int g = 0; g < G; ++g) {
        // B chunk: 4 k-steps x 2 col-fragments = 32 VGPR, from L2 (independent loads)
        bf16x8 b[4][2];
        #pragma unroll
        for (int s = 0; s < 4; ++s)
            #pragma unroll
            for (int c = 0; c < 2; ++c)
                b[s][c] = *(const bf16x8*)(Wt + (size_t)(col0 + (c << 4) + lr) * Ktot + (g << 7) + (s << 5) + (lk << 3));

        #pragma unroll
        for (int tt = 0; tt < RT; ++tt) {
            const int tl = (tt * RW + roww) << 4;
            bf16x8 a[4];
            #pragma unroll
            for (int s = 0; s < 4; ++s) {
                const int c16 = ((s << 2) + lk) ^ (lr & 7);
                a[s] = *(const bf16x8*)&Asl[((g * ROWS + tl + lr) << 7) + (c16 << 3)];
            }
            #pragma unroll
            for (int s = 0; s < 4; ++s) {
                acc[tt][0] = __builtin_amdgcn_mfma_f32_16x16x32_bf16(a[s], b[s][0], acc[tt][0], 0, 0, 0);
                acc[tt][1] = __builtin_amdgcn_mfma_f32_16x16x32_bf16(a[s], b[s][1], acc[tt][1], 0, 0, 0);
            }
        }
    }

    // ---------------- epilogue ----------------
    float bias2[2] = {bias[col0 + lr], bias[col0 + 16 + lr]};

    if (MODE == 3) {
        float g2[2] = {gamma[col0 + lr], gamma[col0 + 16 + lr]};
        float be2[2] = {beta[col0 + lr], beta[col0 + 16 + lr]};
        #pragma unroll
        for (int tt = 0; tt < RT; ++tt) {
            #pragma unroll
            for (int rr = 0; rr < 4; ++rr) {
                int row = tbase + ((tt * RW + roww) << 4) + (lk << 2) + rr;
                int rowc = (row < M) ? row : M - 1;
                float sum = 0.f, sq = 0.f;
                #pragma unroll
                for (int c = 0; c < 2; ++c) {
                    float v = fmaxf(acc[tt][c][rr] + bias2[c], 0.f);
                    v += resid[(size_t)rowc * HH + col0 + (c << 4) + lr];
                    acc[tt][c][rr] = v;
                    sum += v; sq += v * v;
                }
                sum += __shfl_xor(sum, 1); sq += __shfl_xor(sq, 1);
                sum += __shfl_xor(sum, 2); sq += __shfl_xor(sq, 2);
                sum += __shfl_xor(sum, 4); sq += __shfl_xor(sq, 4);
                sum += __shfl_xor(sum, 8); sq += __shfl_xor(sq, 8);
                if (lr == 0) {
                    int rls = (roww << 4) + (lk << 2) + rr;
                    lnbuf[((tt * 32 + rls) << 3) + (colw << 1) + 0] = sum;
                    lnbuf[((tt * 32 + rls) << 3) + (colw << 1) + 1] = sq;
                }
            }
        }
        __syncthreads();
        #pragma unroll
        for (int tt = 0; tt < RT; ++tt) {
            #pragma unroll
            for (int rr = 0; rr < 4; ++rr) {
                int rls = (roww << 4) + (lk << 2) + rr;
                float s4 = 0.f, q4 = 0.f;
                #pragma unroll
                for (int cw = 0; cw < 4; ++cw) {
                    s4 += lnbuf[((tt * 32 + rls) << 3) + (cw << 1) + 0];
                    q4 += lnbuf[((tt * 32 + rls) << 3) + (cw << 1) + 1];
                }
                const float mean = s4 * (1.f / 128.f);
                const float var = q4 * (1.f / 128.f) - mean * mean;
                const float rs = rsqrtf(var + 1e-5f);
                int row = tbase + ((tt * RW + roww) << 4) + (lk << 2) + rr;
                if (row < M) {
                    #pragma unroll
                    for (int c = 0; c < 2; ++c)
                        Cf[(size_t)row * out_ld + col0 + (c << 4) + lr] =
                            (acc[tt][c][rr] - mean) * rs * g2[c] + be2[c];
                }
            }
        }
    } else {
        #pragma unroll
        for (int tt = 0; tt < RT; ++tt) {
            #pragma unroll
            for (int rr = 0; rr < 4; ++rr) {
                int row = tbase + ((tt * RW + roww) << 4) + (lk << 2) + rr;
                if (row >= M) continue;
                #pragma unroll
                for (int c = 0; c < 2; ++c) {
                    float v = acc[tt][c][rr] + bias2[c];
                    if (MODE == 1 || MODE == 4) v = fmaxf(v, 0.f);
                    size_t o = (size_t)row * out_ld + col0 + (c << 4) + lr;
                    if (MODE == 0 || MODE == 1) Cf[o] = v;
                    else Cb[o] = f2bf(v);
                }
            }
        }
    }
}

// ---------------- fused K|V GEMM + attention score (single-barrier version) ----------------
// Per block: 64 edges, 8 col-waves x 32 cols over [Wk|Wv]. K (cols 0..127) is never
// materialized: col-wave h computes s[e,h] = <K-acc+bk, Q[dst[e],h-cols]>/sqrt(32).
// dst[] ids are loaded BEFORE the stage barrier so the epilogue's dst->Q gather
// chain loses one serial hop. V written bf16 [E][128].
template <int RT>
__global__ __launch_bounds__(512, 2) void kv_k(
    const unsigned short* __restrict__ hbf, const int* __restrict__ src,
    const unsigned short* __restrict__ ebf,
    const unsigned short* __restrict__ Wt, const float* __restrict__ bias,
    const float* __restrict__ Q, const int* __restrict__ dst,
    int M, unsigned short* __restrict__ V, float* __restrict__ sbuf)
{
    constexpr int ROWS = RT * 16;
    constexpr int Ktot = 256;
    constexpr int SI = ROWS / 32;
    __shared__ unsigned short Asl[2 * ROWS * 128];

    const int t = threadIdx.x;
    const int wid = t >> 6, lane = t & 63;
    const int lr = lane & 15, lk = lane >> 4;
    const int col0 = wid << 5;
    const int tbase = blockIdx.x * ROWS;

    // early dst-id loads for the score epilogue (wave-uniform branch)
    int dstid[RT][4];
    if (wid < 4) {
        #pragma unroll
        for (int tt = 0; tt < RT; ++tt)
            #pragma unroll
            for (int rr = 0; rr < 4; ++rr) {
                int row = tbase + (tt << 4) + (lk << 2) + rr;
                dstid[tt][rr] = dst[(row < M) ? row : M - 1];
            }
    }

    // stage both chunks (h-gather, e) back-to-back; ONE barrier
    #pragma unroll
    for (int g = 0; g < 2; ++g) {
        const unsigned short* Ag = g ? ebf : hbf;
        #pragma unroll
        for (int i = 0; i < SI; ++i) {
            int rl = ((i * 8 + wid) << 2) + (lane >> 4);
            int gr = tbase + rl; if (gr >= M) gr = M - 1;
            int rid = g ? gr : src[gr];
            const unsigned short* srcp = Ag + (size_t)rid * HH + (((lane & 15) ^ (rl & 7)) << 3);
            unsigned short* dstp = &Asl[(g * ROWS + ((i * 8 + wid) << 2)) << 7];
            __builtin_amdgcn_global_load_lds((const __attribute__((address_space(1))) void*)srcp,
                                             (__attribute__((address_space(3))) void*)dstp, 16, 0, 0);
        }
    }

    f32x4 acc[RT][2];
    #pragma unroll
    for (int tt = 0; tt < RT; ++tt) { acc[tt][0] = (f32x4){0,0,0,0}; acc[tt][1] = (f32x4){0,0,0,0}; }

    __syncthreads();

    #pragma unroll
    for (int g = 0; g < 2; ++g) {
        bf16x8 b[4][2];
        #pragma unroll
        for (int s = 0; s < 4; ++s)
            #pragma unroll
            for (int c = 0; c < 2; ++c)
                b[s][c] = *(const bf16x8*)(Wt + (size_t)(col0 + (c << 4) + lr) * Ktot + (g << 7) + (s << 5) + (lk << 3));

        #pragma unroll
        for (int tt = 0; tt < RT; ++tt) {
            bf16x8 a[4];
            #pragma unroll
            for (int s = 0; s < 4; ++s) {
                const int c16 = ((s << 2) + lk) ^ (lr & 7);
                a[s] = *(const bf16x8*)&Asl[((g * ROWS + (tt << 4) + lr) << 7) + (c16 << 3)];
            }
            #pragma unroll
            for (int s = 0; s < 4; ++s) {
                acc[tt][0] = __builtin_amdgcn_mfma_f32_16x16x32_bf16(a[s], b[s][0], acc[tt][0], 0, 0, 0);
                acc[tt][1] = __builtin_amdgcn_mfma_f32_16x16x32_bf16(a[s], b[s][1], acc[tt][1], 0, 0, 0);
            }
        }
    }

    float bias2[2] = {bias[col0 + lr], bias[col0 + 16 + lr]};

    if (wid < 4) {
        // score epilogue: s[row, head=wid] = <acc+bk, Q[dst[row], head cols]> / sqrt(32)
        #pragma unroll
        for (int tt = 0; tt < RT; ++tt) {
            #pragma unroll
            for (int rr = 0; rr < 4; ++rr) {
                int row = tbase + (tt << 4) + (lk << 2) + rr;
                int d = dstid[tt][rr];
                float q0 = Q[(size_t)d * HH + col0 + lr];
                float q1 = Q[(size_t)d * HH + col0 + 16 + lr];
                float p = (acc[tt][0][rr] + bias2[0]) * q0 + (acc[tt][1][rr] + bias2[1]) * q1;
                p += __shfl_xor(p, 1); p += __shfl_xor(p, 2);
                p += __shfl_xor(p, 4); p += __shfl_xor(p, 8);
                if (lr == 0 && row < M)
                    sbuf[(size_t)row * 4 + wid] = p * 0.17677669529663687f;
            }
        }
    } else {
        // V epilogue: bf16 [E][128]
        #pragma unroll
        for (int tt = 0; tt < RT; ++tt) {
            #pragma unroll
            for (int rr = 0; rr < 4; ++rr) {
                int row = tbase + (tt << 4) + (lk << 2) + rr;
                if (row >= M) continue;
                #pragma unroll
                for (int c = 0; c < 2; ++c)
                    V[(size_t)row * HH + (col0 - 128) + (c << 4) + lr] = f2bf(acc[tt][c][rr] + bias2[c]);
            }
        }
    }
}

// ---------------- per-node online-softmax aggregation (one wave per node) ----------------
__global__ __launch_bounds__(256) void agg_k(const __hip_bfloat16* __restrict__ Vb,
                                             const float* __restrict__ s,
                                             const int* __restrict__ offsets,
                                             const int* __restrict__ eids,
                                             unsigned short* __restrict__ hagg)
{
    const int t = threadIdx.x;
    const int n = blockIdx.x * 4 + (t >> 6);
    if (n >= NN) return;
    const int lane = t & 63;
    const int c0 = lane, c1 = lane + 64;
    const int h0 = lane >> 5, h1 = h0 + 2;
    const int o0 = offsets[n], o1 = offsets[n + 1];
    float m0 = -1e30f, m1 = -1e30f, d0 = 0.f, d1 = 0.f, a0 = 0.f, a1 = 0.f;
    for (int j = o0; j < o1; ++j) {
        const int e = eids[j];
        const float s0 = s[(size_t)e * 4 + h0];
        const float s1 = s[(size_t)e * 4 + h1];
        const float v0 = __bfloat162float(Vb[(size_t)e * HH + c0]);
        const float v1 = __bfloat162float(Vb[(size_t)e * HH + c1]);
        float nm = fmaxf(m0, s0);
        float sc = __expf(m0 - nm);
        float w  = __expf(s0 - nm);
        d0 = d0 * sc + w; a0 = a0 * sc + w * v0; m0 = nm;
        nm = fmaxf(m1, s1);
        sc = __expf(m1 - nm);
        w  = __expf(s1 - nm);
        d1 = d1 * sc + w; a1 = a1 * sc + w * v1; m1 = nm;
    }
    const bool any = (o1 > o0);
    hagg[(size_t)n * HH + c0] = any ? f2bf(a0 / d0) : 0;
    hagg[(size_t)n * HH + c1] = any ? f2bf(a1 / d1) : 0;
}

extern "C" void kernel_launch(void* const* d_in, const int* in_sizes, int n_in,
                              void* d_out, int out_size, void* d_ws, size_t ws_size,
                              hipStream_t stream)
{
    const float* h   = (const float*)d_in[0];
    const float* e   = (const float*)d_in[1];
    const int*   src = (const int*)d_in[2];
    const int*   dst = (const int*)d_in[3];
    const float* Wq  = (const float*)d_in[4];
    const float* bq  = (const float*)d_in[5];
    const float* Wk  = (const float*)d_in[6];
    const float* bk  = (const float*)d_in[7];
    const float* Wv  = (const float*)d_in[8];
    const float* bv  = (const float*)d_in[9];
    const float* Wn1 = (const float*)d_in[10];
    const float* bn1 = (const float*)d_in[11];
    const float* Wn2 = (const float*)d_in[12];
    const float* bn2 = (const float*)d_in[13];
    const float* We1 = (const float*)d_in[14];
    const float* be1 = (const float*)d_in[15];
    const float* We2 = (const float*)d_in[16];
    const float* be2 = (const float*)d_in[17];
    const float* gh  = (const float*)d_in[18];
    const float* bh  = (const float*)d_in[19];
    const float* ge  = (const float*)d_in[20];
    const float* be_ = (const float*)d_in[21];
    (void)in_sizes; (void)n_in; (void)out_size; (void)ws_size;

    float* h_out = (float*)d_out;
    float* e_out = (float*)d_out + (size_t)NN * HH;

    char* ws = (char*)d_ws;
    size_t off = 0;
    auto carve = [&](size_t bytes) { void* p = ws + off; off += (bytes + 255) & ~(size_t)255; return p; };
    unsigned short* Vbuf = (unsigned short*)carve((size_t)EE * HH * 2); // V bf16 [E][128]; reused as t_edge after agg
    unsigned short* t_edge = Vbuf;
    unsigned short* ebf = (unsigned short*)carve((size_t)EE * HH * 2); // e in bf16
    float* Q      = (float*)carve((size_t)NN * HH * 4);                // reused as tnode (bf16) after kv
    unsigned short* tnode = (unsigned short*)Q;
    float* sbuf   = (float*)carve((size_t)EE * 4 * 4);
    unsigned short* hagg = (unsigned short*)carve((size_t)NN * HH * 2); // reused as hobf after Wn1
    unsigned short* hobf = hagg;
    unsigned short* hbf  = (unsigned short*)carve((size_t)NN * HH * 2);
    int* cursor   = (int*)carve((size_t)NN * 4);
    int* offsets  = (int*)carve((size_t)(NN + 1) * 4);
    int* bsum     = (int*)carve(256 * 4);
    int* eids     = (int*)carve((size_t)EE * 4);
    unsigned short* Wq_s  = (unsigned short*)carve(128 * 128 * 2);
    unsigned short* Wkv_s = (unsigned short*)carve(256 * 256 * 2);
    unsigned short* Wn1_s = (unsigned short*)carve(128 * 128 * 2);
    unsigned short* Wn2_s = (unsigned short*)carve(128 * 128 * 2);
    unsigned short* We1_s = (unsigned short*)carve(128 * 384 * 2);
    unsigned short* We2_s = (unsigned short*)carve(128 * 128 * 2);
    float* b_kv   = (float*)carve(256 * 4);

    const int nb = (NN + 255) / 256;

    // weight prep (bf16 transpose) + combined KV bias
    wprep_k<<<(128 * 128 + 255) / 256, 256, 0, stream>>>(Wq,  Wq_s,  128, 128, 0, 128);
    wprep_k<<<(256 * 128 + 255) / 256, 256, 0, stream>>>(Wk,  Wkv_s, 256, 128, 0, 256);
    wprep_k<<<(256 * 128 + 255) / 256, 256, 0, stream>>>(Wv,  Wkv_s, 256, 128, 128, 256);
    wprep_k<<<(128 * 128 + 255) / 256, 256, 0, stream>>>(Wn1, Wn1_s, 128, 128, 0, 128);
    wprep_k<<<(128 * 128 + 255) / 256, 256, 0, stream>>>(Wn2, Wn2_s, 128, 128, 0, 128);
    wprep_k<<<(384 * 128 + 255) / 256, 256, 0, stream>>>(We1, We1_s, 384, 128, 0, 384);
    wprep_k<<<(128 * 128 + 255) / 256, 256, 0, stream>>>(We2, We2_s, 128, 128, 0, 128);
    hipMemcpyAsync(b_kv,       bk, 128 * 4, hipMemcpyDeviceToDevice, stream);
    hipMemcpyAsync(b_kv + 128, bv, 128 * 4, hipMemcpyDeviceToDevice, stream);

    // activations -> bf16 (one-time; same rounding as the old inline f2bf path)
    cvt_k<<<(NN * HH / 8 + 255) / 256, 256, 0, stream>>>(h, hbf, (long)NN * HH / 8);
    cvt_k<<<(EE * HH / 8 + 255) / 256, 256, 0, stream>>>(e, ebf, (long)EE * HH / 8);

    // CSR build
    hipMemsetAsync(cursor, 0, (size_t)NN * 4, stream);
    hist_k<<<(EE + 255) / 256, 256, 0, stream>>>(dst, cursor);
    blocksum_k<<<nb, 256, 0, stream>>>(cursor, bsum);
    scanb_k<<<1, 256, 0, stream>>>(bsum, nb);
    offsets_k<<<nb, 256, 0, stream>>>(cursor, bsum, offsets, cursor);
    fill_k<<<(EE + 255) / 256, 256, 0, stream>>>(dst, cursor, eids);

    // Q = h @ Wq + bq  (f32 out)  [128 rows x 128 cols per block; LDS 32KB]
    mm4_k<1, 4, 4, 0><<<(NN + 127) / 128, 512, 0, stream>>>(
        hbf, nullptr, nullptr, nullptr, nullptr, nullptr,
        Wq_s, bq, NN, Q, nullptr, 128, nullptr, nullptr, nullptr);

    // fused K|V GEMM + score: V bf16 [E][128] + s[E][4]; K never materialized; LDS 32KB
    kv_k<4><<<EE / 64, 512, 0, stream>>>(
        hbf, src, ebf, Wkv_s, b_kv, Q, dst, EE, Vbuf, sbuf);

    agg_k<<<(NN + 3) / 4, 256, 0, stream>>>((const __hip_bfloat16*)Vbuf, sbuf, offsets, eids, hagg);

    // node MLP + residual + LN -> h_out
    mm4_k<1, 4, 4, 4><<<(NN + 127) / 128, 512, 0, stream>>>(
        hagg, nullptr, nullptr, nullptr, nullptr, nullptr,
        Wn1_s, bn1, NN, nullptr, tnode, 128, nullptr, nullptr, nullptr);
    mm4_k<1, 4, 4, 3><<<(NN + 127) / 128, 512, 0, stream>>>(
        tnode, nullptr, nullptr, nullptr, nullptr, nullptr,
        Wn2_s, bn2, NN, h_out, nullptr, 128, h, gh, bh);

    // h_out -> bf16 for the edge-MLP gathers
    cvt_k<<<(NN * HH / 8 + 255) / 256, 256, 0, stream>>>(h_out, hobf, (long)NN * HH / 8);

    // edge MLP on [h_out[src], h_out[dst], e] + residual + LN -> e_out
    // We1: G=3, 64 rows/block, LDS 48KB (3 blocks/CU)
    mm4_k<3, 4, 2, 4><<<EE / 64, 512, 0, stream>>>(
        hobf, src, hobf, dst, ebf, nullptr,
        We1_s, be1, EE, nullptr, t_edge, 128, nullptr, nullptr, nullptr);
    mm4_k<1, 4, 4, 3><<<EE / 128, 512, 0, stream>>>(
        t_edge, nullptr, nullptr, nullptr, nullptr, nullptr,
        We2_s, be2, EE, e_out, nullptr, 128, e, ge, be_);
}